// Round 1
// baseline (2100.215 us; speedup 1.0000x reference)
//
#include <hip/hip_runtime.h>
#include <math.h>

#define N_NODES 50000
#define N_EDGES 20000
#define NNZ_C   1000000
#define F_IN    128
#define HID     64
#define NCLS    40
#define NLAYER  4
#define ALPHA   0.1f

// ---------------- Kernel 1: X = relu(x @ W0 + b0); X0 = X ----------------
__global__ __launch_bounds__(256) void input_gemm(
    const float* __restrict__ x, const float* __restrict__ W0,
    const float* __restrict__ b0, float* __restrict__ X, float* __restrict__ X0)
{
    __shared__ float w[F_IN * HID];          // 32 KB
    int tid = threadIdx.x;
    for (int i = tid; i < F_IN * HID; i += 256) w[i] = W0[i];
    __syncthreads();
    int row = blockIdx.x * 4 + (tid >> 6);
    int col = tid & 63;
    if (row >= N_NODES) return;
    const float* xr = x + (long long)row * F_IN;
    float acc = 0.f;
    #pragma unroll 8
    for (int k = 0; k < F_IN; ++k) acc += xr[k] * w[k * HID + col];
    float v = acc + b0[col];
    v = v > 0.f ? v : 0.f;
    X [row * HID + col] = v;
    X0[row * HID + col] = v;
}

// ---------------- degree counts + reciprocal ----------------
__global__ __launch_bounds__(256) void degrees(
    const int* __restrict__ vertex, const int* __restrict__ edges,
    float* __restrict__ cnt_e, float* __restrict__ cnt_v)
{
    int i = blockIdx.x * blockDim.x + threadIdx.x;
    if (i < NNZ_C) {
        atomicAdd(&cnt_e[edges[i]],  1.0f);
        atomicAdd(&cnt_v[vertex[i]], 1.0f);
    }
}

__global__ __launch_bounds__(256) void invert(float* __restrict__ buf, int n)
{
    int i = blockIdx.x * blockDim.x + threadIdx.x;
    if (i < n) buf[i] = 1.0f / fmaxf(buf[i], 1.0f);
}

// ---------------- scatter: Xe[e] += X[v]  (sum; mean folded later) ----------------
__global__ __launch_bounds__(256) void scatter_ve(
    const float* __restrict__ X, const int* __restrict__ vertex,
    const int* __restrict__ edges, float* __restrict__ Xe)
{
    int t = blockIdx.x * blockDim.x + threadIdx.x;   // < 64M, fits int32
    int i = t >> 6;          // nnz index (one wave per nnz)
    int f = t & 63;          // feature = lane
    if (i >= NNZ_C) return;
    int v = vertex[i];
    int e = edges[i];
    atomicAdd(&Xe[e * HID + f], X[v * HID + f]);
}

// ---------------- scatter: Xv[v] += Xe[e] * inv_e[e] ----------------
__global__ __launch_bounds__(256) void scatter_ev(
    const float* __restrict__ Xe, const float* __restrict__ inv_e,
    const int* __restrict__ vertex, const int* __restrict__ edges,
    float* __restrict__ Xv)
{
    int t = blockIdx.x * blockDim.x + threadIdx.x;
    int i = t >> 6;
    int f = t & 63;
    if (i >= NNZ_C) return;
    int v = vertex[i];
    int e = edges[i];
    atomicAdd(&Xv[v * HID + f], Xe[e * HID + f] * inv_e[e]);
}

// ---------------- node update: mean -> l2norm -> alpha-mix -> (1-b)I+b*Ws GEMM -> relu ----------------
__global__ __launch_bounds__(256) void node_update(
    const float* __restrict__ Xv, const float* __restrict__ inv_v,
    const float* __restrict__ X0, const float* __restrict__ Wl,
    float* __restrict__ X, float beta)
{
    __shared__ float w[HID * HID];           // 16 KB
    __shared__ float xi[4][HID];             // 1 KB
    int tid = threadIdx.x;
    for (int i = tid; i < HID * HID; i += 256) w[i] = Wl[i];
    int row = blockIdx.x * 4 + (tid >> 6);
    int f   = tid & 63;
    int wv  = tid >> 6;
    float xif = 0.f;
    if (row < N_NODES) {
        float mean = Xv[row * HID + f] * inv_v[row];
        float s = mean * mean;
        #pragma unroll
        for (int o = 32; o > 0; o >>= 1) s += __shfl_xor(s, o, 64);
        float norm  = sqrtf(s);
        float scale = norm > 0.f ? 1.0f / norm : 0.f;
        xif = (1.0f - ALPHA) * (mean * scale) + ALPHA * X0[row * HID + f];
    }
    xi[wv][f] = xif;
    __syncthreads();
    if (row >= N_NODES) return;
    float acc = 0.f;
    #pragma unroll
    for (int k = 0; k < HID; ++k) acc += xi[wv][k] * w[k * HID + f];
    float y = (1.0f - beta) * xif + beta * acc;
    X[row * HID + f] = y > 0.f ? y : 0.f;
}

// ---------------- out = X @ Wout + bout ----------------
__global__ __launch_bounds__(256) void out_gemm(
    const float* __restrict__ X, const float* __restrict__ Wout,
    const float* __restrict__ bout, float* __restrict__ out)
{
    __shared__ float w[HID * NCLS];          // 10.2 KB
    __shared__ float xr[4][HID];
    int tid = threadIdx.x;
    for (int i = tid; i < HID * NCLS; i += 256) w[i] = Wout[i];
    int row = blockIdx.x * 4 + (tid >> 6);
    int f   = tid & 63;
    int wv  = tid >> 6;
    float xv = 0.f;
    if (row < N_NODES) xv = X[row * HID + f];
    xr[wv][f] = xv;
    __syncthreads();
    if (row >= N_NODES || f >= NCLS) return;
    float acc = bout[f];
    #pragma unroll
    for (int k = 0; k < HID; ++k) acc += xr[wv][k] * w[k * NCLS + f];
    out[row * NCLS + f] = acc;
}

extern "C" void kernel_launch(void* const* d_in, const int* in_sizes, int n_in,
                              void* d_out, int out_size, void* d_ws, size_t ws_size,
                              hipStream_t stream)
{
    const float* x      = (const float*)d_in[0];
    const int*   vertex = (const int*)  d_in[1];
    const int*   edges  = (const int*)  d_in[2];
    const float* W0     = (const float*)d_in[3];
    const float* b0     = (const float*)d_in[4];
    const float* Ws     = (const float*)d_in[5];
    const float* Wout   = (const float*)d_in[6];
    const float* bout   = (const float*)d_in[7];
    float* out = (float*)d_out;

    float* ws    = (float*)d_ws;
    float* X     = ws;                         // N*HID
    float* X0    = X  + (size_t)N_NODES * HID; // N*HID
    float* Xv    = X0 + (size_t)N_NODES * HID; // N*HID
    float* Xe    = Xv + (size_t)N_NODES * HID; // NE*HID
    float* inv_e = Xe + (size_t)N_EDGES * HID; // NE
    float* inv_v = inv_e + N_EDGES;            // N   (contiguous with inv_e)

    // degree counts (zero, count, invert) — once per call, reused across layers
    hipMemsetAsync(inv_e, 0, (size_t)(N_EDGES + N_NODES) * sizeof(float), stream);
    degrees<<<(NNZ_C + 255) / 256, 256, 0, stream>>>(vertex, edges, inv_e, inv_v);
    invert<<<(N_EDGES + N_NODES + 255) / 256, 256, 0, stream>>>(inv_e, N_EDGES + N_NODES);

    input_gemm<<<(N_NODES + 3) / 4, 256, 0, stream>>>(x, W0, b0, X, X0);

    const int scat_blocks = (NNZ_C * HID) / 256;   // 250000
    for (int l = 0; l < NLAYER; ++l) {
        float beta = logf(0.5f / (float)(l + 1) + 1.0f);
        hipMemsetAsync(Xe, 0, (size_t)N_EDGES * HID * sizeof(float), stream);
        scatter_ve<<<scat_blocks, 256, 0, stream>>>(X, vertex, edges, Xe);
        hipMemsetAsync(Xv, 0, (size_t)N_NODES * HID * sizeof(float), stream);
        scatter_ev<<<scat_blocks, 256, 0, stream>>>(Xe, inv_e, vertex, edges, Xv);
        node_update<<<(N_NODES + 3) / 4, 256, 0, stream>>>(
            Xv, inv_v, X0, Ws + (size_t)l * HID * HID, X, beta);
    }

    out_gemm<<<(N_NODES + 3) / 4, 256, 0, stream>>>(X, Wout, bout, out);
}

// Round 2
// 966.204 us; speedup vs baseline: 2.1737x; 2.1737x over previous
//
#include <hip/hip_runtime.h>
#include <math.h>

#define N_NODES 50000
#define N_EDGES 20000
#define NNZ_C   1000000
#define F_IN    128
#define HID     64
#define NCLS    40
#define NLAYER  4
#define ALPHA   0.1f

// ---------------- X = relu(x @ W0 + b0); X0 = X ----------------
__global__ __launch_bounds__(256) void input_gemm(
    const float* __restrict__ x, const float* __restrict__ W0,
    const float* __restrict__ b0, float* __restrict__ X, float* __restrict__ X0)
{
    __shared__ float w[F_IN * HID];          // 32 KB
    int tid = threadIdx.x;
    for (int i = tid; i < F_IN * HID; i += 256) w[i] = W0[i];
    __syncthreads();
    int row = blockIdx.x * 4 + (tid >> 6);
    int col = tid & 63;
    if (row >= N_NODES) return;
    const float4* xr4 = (const float4*)(x + (long long)row * F_IN);
    float acc = 0.f;
    #pragma unroll
    for (int k = 0; k < F_IN / 4; ++k) {
        float4 xv = xr4[k];
        acc += xv.x * w[(4 * k + 0) * HID + col];
        acc += xv.y * w[(4 * k + 1) * HID + col];
        acc += xv.z * w[(4 * k + 2) * HID + col];
        acc += xv.w * w[(4 * k + 3) * HID + col];
    }
    float v = acc + b0[col];
    v = v > 0.f ? v : 0.f;
    X [row * HID + col] = v;
    X0[row * HID + col] = v;
}

// ---------------- int degree histogram ----------------
__global__ __launch_bounds__(256) void degrees(
    const int* __restrict__ vertex, const int* __restrict__ edges,
    int* __restrict__ cnt_e, int* __restrict__ cnt_v)
{
    int i = blockIdx.x * blockDim.x + threadIdx.x;
    if (i < NNZ_C) {
        atomicAdd(&cnt_e[edges[i]],  1);
        atomicAdd(&cnt_v[vertex[i]], 1);
    }
}

// ---------------- single-block exclusive scan + inv + cursor init ----------------
__global__ __launch_bounds__(1024) void scan_kernel(
    const int* __restrict__ cnt, int* __restrict__ off, int* __restrict__ cur,
    float* __restrict__ inv, int n)
{
    __shared__ int chunk_sum[1024];
    __shared__ int chunk_off[1024];
    int tid = threadIdx.x;
    int chunk = (n + 1023) / 1024;
    int b = tid * chunk;
    int e = b + chunk; if (e > n) e = n;
    int s = 0;
    for (int i = b; i < e; ++i) s += cnt[i];
    chunk_sum[tid] = s;
    __syncthreads();
    if (tid == 0) {
        int run = 0;
        for (int i = 0; i < 1024; ++i) { chunk_off[i] = run; run += chunk_sum[i]; }
    }
    __syncthreads();
    int run = chunk_off[tid];
    for (int i = b; i < e; ++i) {
        off[i] = run; cur[i] = run;
        inv[i] = 1.0f / fmaxf((float)cnt[i], 1.0f);
        run += cnt[i];
    }
    if (e == n && b < n) off[n] = run;   // last active thread writes total
}

// ---------------- build adjacency (counting-sort scatter) ----------------
__global__ __launch_bounds__(256) void build_adj(
    const int* __restrict__ vertex, const int* __restrict__ edges,
    int* __restrict__ cur_e, int* __restrict__ cur_v,
    int* __restrict__ adj_e, int* __restrict__ adj_v)
{
    int i = blockIdx.x * blockDim.x + threadIdx.x;
    if (i >= NNZ_C) return;
    int v = vertex[i], e = edges[i];
    adj_e[atomicAdd(&cur_e[e], 1)] = v;   // vertices grouped by edge
    adj_v[atomicAdd(&cur_v[v], 1)] = e;   // edges grouped by vertex
}

// ---------------- Xe[e] = inv_e[e] * sum_{v in adj_e[e]} X[v]  (gather) ----------------
__global__ __launch_bounds__(256) void edge_gather(
    const float* __restrict__ X, const int* __restrict__ adj_e,
    const int* __restrict__ off_e, const float* __restrict__ inv_e,
    float* __restrict__ Xe)
{
    int wid  = (blockIdx.x * 256 + threadIdx.x) >> 6;   // edge id
    int lane = threadIdx.x & 63;
    if (wid >= N_EDGES) return;
    int beg = off_e[wid], end = off_e[wid + 1];
    float acc = 0.f;
    for (int j = beg; j < end; j += 64) {
        int nj = end - j; if (nj > 64) nj = 64;
        int myidx = (lane < nj) ? adj_e[j + lane] : 0;   // coalesced index load
        int k = 0;
        for (; k + 3 < nj; k += 4) {
            int i0 = __shfl(myidx, k);
            int i1 = __shfl(myidx, k + 1);
            int i2 = __shfl(myidx, k + 2);
            int i3 = __shfl(myidx, k + 3);
            float t0 = X[i0 * HID + lane];
            float t1 = X[i1 * HID + lane];
            float t2 = X[i2 * HID + lane];
            float t3 = X[i3 * HID + lane];
            acc += (t0 + t1) + (t2 + t3);
        }
        for (; k < nj; ++k) {
            int i0 = __shfl(myidx, k);
            acc += X[i0 * HID + lane];
        }
    }
    Xe[wid * HID + lane] = acc * inv_e[wid];
}

// ---------------- node side fused: gather-mean -> l2norm -> alpha-mix -> (1-b)I+b*Ws -> relu ----------------
__global__ __launch_bounds__(256) void node_fused(
    const float* __restrict__ Xe, const int* __restrict__ adj_v,
    const int* __restrict__ off_v, const float* __restrict__ inv_v,
    const float* __restrict__ X0, const float* __restrict__ Wl,
    float* __restrict__ X, float beta)
{
    __shared__ float w[HID * HID];           // 16 KB
    int tid = threadIdx.x;
    for (int i = tid; i < HID * HID; i += 256) w[i] = Wl[i];
    __syncthreads();
    int row  = blockIdx.x * 4 + (tid >> 6);  // node id (one wave per node)
    int lane = tid & 63;
    if (row >= N_NODES) return;
    int beg = off_v[row], end = off_v[row + 1];
    float acc = 0.f;
    for (int j = beg; j < end; j += 64) {
        int nj = end - j; if (nj > 64) nj = 64;
        int myidx = (lane < nj) ? adj_v[j + lane] : 0;
        int k = 0;
        for (; k + 3 < nj; k += 4) {
            int i0 = __shfl(myidx, k);
            int i1 = __shfl(myidx, k + 1);
            int i2 = __shfl(myidx, k + 2);
            int i3 = __shfl(myidx, k + 3);
            float t0 = Xe[i0 * HID + lane];
            float t1 = Xe[i1 * HID + lane];
            float t2 = Xe[i2 * HID + lane];
            float t3 = Xe[i3 * HID + lane];
            acc += (t0 + t1) + (t2 + t3);
        }
        for (; k < nj; ++k) {
            int i0 = __shfl(myidx, k);
            acc += Xe[i0 * HID + lane];
        }
    }
    float mean = acc * inv_v[row];
    // row L2 norm across 64 lanes
    float s = mean * mean;
    #pragma unroll
    for (int o = 32; o > 0; o >>= 1) s += __shfl_xor(s, o, 64);
    float norm  = sqrtf(s);
    float scale = norm > 0.f ? 1.0f / norm : 0.f;
    float xif = (1.0f - ALPHA) * (mean * scale) + ALPHA * X0[row * HID + lane];
    // y = (1-beta)*xi + beta*(xi @ W);  xi broadcast via shfl
    float gacc = 0.f;
    #pragma unroll
    for (int k = 0; k < HID; ++k)
        gacc += __shfl(xif, k) * w[k * HID + lane];
    float y = (1.0f - beta) * xif + beta * gacc;
    X[row * HID + lane] = y > 0.f ? y : 0.f;
}

// ---------------- out = X @ Wout + bout ----------------
__global__ __launch_bounds__(256) void out_gemm(
    const float* __restrict__ X, const float* __restrict__ Wout,
    const float* __restrict__ bout, float* __restrict__ out)
{
    __shared__ float w[HID * NCLS];          // 10.2 KB
    __shared__ float xr[4][HID];
    int tid = threadIdx.x;
    for (int i = tid; i < HID * NCLS; i += 256) w[i] = Wout[i];
    int row = blockIdx.x * 4 + (tid >> 6);
    int f   = tid & 63;
    int wv  = tid >> 6;
    float xv = 0.f;
    if (row < N_NODES) xv = X[row * HID + f];
    xr[wv][f] = xv;
    __syncthreads();
    if (row >= N_NODES || f >= NCLS) return;
    float acc = bout[f];
    #pragma unroll
    for (int k = 0; k < HID; ++k) acc += xr[wv][k] * w[k * NCLS + f];
    out[row * NCLS + f] = acc;
}

extern "C" void kernel_launch(void* const* d_in, const int* in_sizes, int n_in,
                              void* d_out, int out_size, void* d_ws, size_t ws_size,
                              hipStream_t stream)
{
    const float* x      = (const float*)d_in[0];
    const int*   vertex = (const int*)  d_in[1];
    const int*   edges  = (const int*)  d_in[2];
    const float* W0     = (const float*)d_in[3];
    const float* b0     = (const float*)d_in[4];
    const float* Ws     = (const float*)d_in[5];
    const float* Wout   = (const float*)d_in[6];
    const float* bout   = (const float*)d_in[7];
    float* out = (float*)d_out;

    char* ws = (char*)d_ws;
    float* X     = (float*)ws;                 ws += (size_t)N_NODES * HID * 4;
    float* X0    = (float*)ws;                 ws += (size_t)N_NODES * HID * 4;
    float* Xe    = (float*)ws;                 ws += (size_t)N_EDGES * HID * 4;
    int*   adj_e = (int*)ws;                   ws += (size_t)NNZ_C * 4;
    int*   adj_v = (int*)ws;                   ws += (size_t)NNZ_C * 4;
    int*   off_e = (int*)ws;                   ws += (size_t)(N_EDGES + 1) * 4;
    int*   off_v = (int*)ws;                   ws += (size_t)(N_NODES + 1) * 4;
    int*   cur_e = (int*)ws;                   ws += (size_t)N_EDGES * 4;
    int*   cur_v = (int*)ws;                   ws += (size_t)N_NODES * 4;
    int*   cnt_e = (int*)ws;                   ws += (size_t)N_EDGES * 4;
    int*   cnt_v = (int*)ws;                   ws += (size_t)N_NODES * 4;
    float* inv_e = (float*)ws;                 ws += (size_t)N_EDGES * 4;
    float* inv_v = (float*)ws;                 ws += (size_t)N_NODES * 4;

    // ---- CSR build (once per call) ----
    hipMemsetAsync(cnt_e, 0, (size_t)(N_EDGES + N_NODES) * 4, stream);  // cnt_e,cnt_v contiguous
    degrees<<<(NNZ_C + 255) / 256, 256, 0, stream>>>(vertex, edges, cnt_e, cnt_v);
    scan_kernel<<<1, 1024, 0, stream>>>(cnt_e, off_e, cur_e, inv_e, N_EDGES);
    scan_kernel<<<1, 1024, 0, stream>>>(cnt_v, off_v, cur_v, inv_v, N_NODES);
    build_adj<<<(NNZ_C + 255) / 256, 256, 0, stream>>>(vertex, edges, cur_e, cur_v, adj_e, adj_v);

    input_gemm<<<(N_NODES + 3) / 4, 256, 0, stream>>>(x, W0, b0, X, X0);

    for (int l = 0; l < NLAYER; ++l) {
        float beta = logf(0.5f / (float)(l + 1) + 1.0f);
        edge_gather<<<(N_EDGES * 64 + 255) / 256, 256, 0, stream>>>(X, adj_e, off_e, inv_e, Xe);
        node_fused<<<(N_NODES + 3) / 4, 256, 0, stream>>>(
            Xe, adj_v, off_v, inv_v, X0, Ws + (size_t)l * HID * HID, X, beta);
    }

    out_gemm<<<(N_NODES + 3) / 4, 256, 0, stream>>>(X, Wout, bout, out);
}

// Round 3
// 761.104 us; speedup vs baseline: 2.7594x; 1.2695x over previous
//
#include <hip/hip_runtime.h>
#include <hip/hip_fp16.h>
#include <math.h>

#define N_NODES 50000
#define N_EDGES 20000
#define NNZ_C   1000000
#define F_IN    128
#define HID     64
#define NCLS    40
#define NLAYER  4
#define ALPHA   0.1f

#define ESHIFT  6                      // 64 edges / bucket
#define VSHIFT  7                      // 128 vertices / bucket
#define NB_E    ((N_EDGES + 63) / 64)    // 313
#define NB_V    ((N_NODES + 127) / 128)  // 391
#define MAXNB   391

// ---------------- X0 = relu(x @ W0 + b0) fp32; Xh = fp16 copy ----------------
__global__ __launch_bounds__(256) void input_gemm(
    const float* __restrict__ x, const float* __restrict__ W0,
    const float* __restrict__ b0, float* __restrict__ X0, __half* __restrict__ Xh)
{
    __shared__ float w[F_IN * HID];          // 32 KB
    int tid = threadIdx.x;
    for (int i = tid; i < F_IN * HID; i += 256) w[i] = W0[i];
    __syncthreads();
    int row = blockIdx.x * 4 + (tid >> 6);
    int col = tid & 63;
    if (row >= N_NODES) return;
    const float4* xr4 = (const float4*)(x + (long long)row * F_IN);
    float acc = 0.f;
    #pragma unroll
    for (int k = 0; k < F_IN / 4; ++k) {
        float4 xv = xr4[k];
        acc += xv.x * w[(4 * k + 0) * HID + col];
        acc += xv.y * w[(4 * k + 1) * HID + col];
        acc += xv.z * w[(4 * k + 2) * HID + col];
        acc += xv.w * w[(4 * k + 3) * HID + col];
    }
    float v = acc + b0[col];
    v = v > 0.f ? v : 0.f;
    X0[row * HID + col] = v;
    Xh[row * HID + col] = __float2half(v);
}

// ---------------- degree histogram ----------------
__global__ __launch_bounds__(256) void degrees(
    const int* __restrict__ vertex, const int* __restrict__ edges,
    int* __restrict__ cnt_e, int* __restrict__ cnt_v)
{
    int i = blockIdx.x * blockDim.x + threadIdx.x;
    if (i < NNZ_C) {
        atomicAdd(&cnt_e[edges[i]],  1);
        atomicAdd(&cnt_v[vertex[i]], 1);
    }
}

// ---------------- single-block exclusive scan + inv ----------------
__global__ __launch_bounds__(1024) void scan_kernel(
    const int* __restrict__ cnt, int* __restrict__ off,
    float* __restrict__ inv, int n)
{
    __shared__ int csum[1024];
    int tid = threadIdx.x;
    int chunk = (n + 1023) / 1024;
    int b = tid * chunk;
    int e = b + chunk; if (e > n) e = n;
    int s = 0;
    for (int i = b; i < e; ++i) s += cnt[i];
    csum[tid] = s;
    __syncthreads();
    for (int d = 1; d < 1024; d <<= 1) {          // Hillis-Steele inclusive
        int t = (tid >= d) ? csum[tid - d] : 0;
        __syncthreads();
        csum[tid] += t;
        __syncthreads();
    }
    int run = (tid == 0) ? 0 : csum[tid - 1];
    for (int i = b; i < e; ++i) {
        off[i] = run;
        inv[i] = 1.0f / fmaxf((float)cnt[i], 1.0f);
        run += cnt[i];
    }
    if (tid == 1023) off[n] = csum[1023];
}

__global__ void init_cur(const int* __restrict__ off, int shift, int nb,
                         int* __restrict__ cur)
{
    int b = blockIdx.x * blockDim.x + threadIdx.x;
    if (b < nb) cur[b] = off[b << shift];
}

// ---------------- pass 1: bin pairs into coarse buckets (LDS hist, run writes) ----------------
__global__ __launch_bounds__(256) void bin_pass1(
    const int* __restrict__ keys, const int* __restrict__ vals,
    int shift, int nb, int* __restrict__ cur,
    unsigned long long* __restrict__ binned)
{
    __shared__ int hist[MAXNB];
    __shared__ int base[MAXNB];
    int tid = threadIdx.x;
    int blk = blockIdx.x * 4096;
    int nh = NNZ_C - blk; if (nh > 4096) nh = 4096;
    for (int i = tid; i < nb; i += 256) hist[i] = 0;
    __syncthreads();
    for (int i = tid; i < nh; i += 256)
        atomicAdd(&hist[keys[blk + i] >> shift], 1);
    __syncthreads();
    for (int i = tid; i < nb; i += 256) {
        int c = hist[i];
        base[i] = c ? atomicAdd(&cur[i], c) : 0;
        hist[i] = 0;
    }
    __syncthreads();
    for (int i = tid; i < nh; i += 256) {
        int k = keys[blk + i], v = vals[blk + i];
        int bkt = k >> shift;
        int r = atomicAdd(&hist[bkt], 1);
        binned[base[bkt] + r] = ((unsigned long long)(unsigned)k << 32) | (unsigned)v;
    }
}

// ---------------- pass 2: one block per bucket, finish counting sort ----------------
__global__ __launch_bounds__(256) void bin_pass2(
    const unsigned long long* __restrict__ binned, const int* __restrict__ off,
    int shift, int nkeys, int* __restrict__ adj)
{
    __shared__ int cur[128];
    int b  = blockIdx.x;
    int k0 = b << shift;
    int bs = 1 << shift;
    int kn = nkeys - k0; if (kn > bs) kn = bs;
    for (int i = threadIdx.x; i < kn; i += 256) cur[i] = off[k0 + i];
    __syncthreads();
    int beg = off[k0];
    int end = off[k0 + kn];
    for (int j = beg + threadIdx.x; j < end; j += 256) {
        unsigned long long p = binned[j];
        int k = (int)(p >> 32);
        int v = (int)(p & 0xffffffffULL);
        int pos = atomicAdd(&cur[k - k0], 1);
        adj[pos] = v;
    }
}

// ---------------- Xe[e] = inv_e[e] * sum_{v in adj_e[e]} X[v]  (fp16 gather) ----------------
__global__ __launch_bounds__(256) void edge_gather(
    const __half* __restrict__ Xh, const int* __restrict__ adj_e,
    const int* __restrict__ off_e, const float* __restrict__ inv_e,
    __half* __restrict__ Xeh)
{
    int wid  = (blockIdx.x * 256 + threadIdx.x) >> 6;   // edge id
    int lane = threadIdx.x & 63;
    if (wid >= N_EDGES) return;
    int beg = off_e[wid], end = off_e[wid + 1];
    float acc = 0.f;
    for (int j = beg; j < end; j += 64) {
        int nj = end - j; if (nj > 64) nj = 64;
        int myidx = (lane < nj) ? adj_e[j + lane] : 0;
        int k = 0;
        for (; k + 3 < nj; k += 4) {
            int i0 = __shfl(myidx, k);
            int i1 = __shfl(myidx, k + 1);
            int i2 = __shfl(myidx, k + 2);
            int i3 = __shfl(myidx, k + 3);
            float t0 = __half2float(Xh[i0 * HID + lane]);
            float t1 = __half2float(Xh[i1 * HID + lane]);
            float t2 = __half2float(Xh[i2 * HID + lane]);
            float t3 = __half2float(Xh[i3 * HID + lane]);
            acc += (t0 + t1) + (t2 + t3);
        }
        for (; k < nj; ++k) {
            int i0 = __shfl(myidx, k);
            acc += __half2float(Xh[i0 * HID + lane]);
        }
    }
    Xeh[wid * HID + lane] = __float2half(acc * inv_e[wid]);
}

// ---------------- node fused: gather-mean -> l2norm -> alpha-mix -> (1-b)I+b*Ws -> relu ----------------
__global__ __launch_bounds__(256) void node_fused(
    const __half* __restrict__ Xeh, const int* __restrict__ adj_v,
    const int* __restrict__ off_v, const float* __restrict__ inv_v,
    const float* __restrict__ X0, const float* __restrict__ Wl,
    __half* __restrict__ Xh, float beta)
{
    __shared__ float w[HID * HID];           // 16 KB
    int tid = threadIdx.x;
    for (int i = tid; i < HID * HID; i += 256) w[i] = Wl[i];
    __syncthreads();
    int row  = blockIdx.x * 4 + (tid >> 6);  // node id (one wave per node)
    int lane = tid & 63;
    if (row >= N_NODES) return;
    int beg = off_v[row], end = off_v[row + 1];
    float acc = 0.f;
    for (int j = beg; j < end; j += 64) {
        int nj = end - j; if (nj > 64) nj = 64;
        int myidx = (lane < nj) ? adj_v[j + lane] : 0;
        int k = 0;
        for (; k + 3 < nj; k += 4) {
            int i0 = __shfl(myidx, k);
            int i1 = __shfl(myidx, k + 1);
            int i2 = __shfl(myidx, k + 2);
            int i3 = __shfl(myidx, k + 3);
            float t0 = __half2float(Xeh[i0 * HID + lane]);
            float t1 = __half2float(Xeh[i1 * HID + lane]);
            float t2 = __half2float(Xeh[i2 * HID + lane]);
            float t3 = __half2float(Xeh[i3 * HID + lane]);
            acc += (t0 + t1) + (t2 + t3);
        }
        for (; k < nj; ++k) {
            int i0 = __shfl(myidx, k);
            acc += __half2float(Xeh[i0 * HID + lane]);
        }
    }
    float mean = acc * inv_v[row];
    float s = mean * mean;
    #pragma unroll
    for (int o = 32; o > 0; o >>= 1) s += __shfl_xor(s, o, 64);
    float norm  = sqrtf(s);
    float scale = norm > 0.f ? 1.0f / norm : 0.f;
    float xif = (1.0f - ALPHA) * (mean * scale) + ALPHA * X0[row * HID + lane];
    float gacc = 0.f;
    #pragma unroll
    for (int k = 0; k < HID; ++k)
        gacc += __shfl(xif, k) * w[k * HID + lane];
    float y = (1.0f - beta) * xif + beta * gacc;
    Xh[row * HID + lane] = __float2half(y > 0.f ? y : 0.f);
}

// ---------------- out = X @ Wout + bout ----------------
__global__ __launch_bounds__(256) void out_gemm(
    const __half* __restrict__ Xh, const float* __restrict__ Wout,
    const float* __restrict__ bout, float* __restrict__ out)
{
    __shared__ float w[HID * NCLS];          // 10.2 KB
    __shared__ float xr[4][HID];
    int tid = threadIdx.x;
    for (int i = tid; i < HID * NCLS; i += 256) w[i] = Wout[i];
    int row = blockIdx.x * 4 + (tid >> 6);
    int f   = tid & 63;
    int wv  = tid >> 6;
    float xv = 0.f;
    if (row < N_NODES) xv = __half2float(Xh[row * HID + f]);
    xr[wv][f] = xv;
    __syncthreads();
    if (row >= N_NODES || f >= NCLS) return;
    float acc = bout[f];
    #pragma unroll
    for (int k = 0; k < HID; ++k) acc += xr[wv][k] * w[k * NCLS + f];
    out[row * NCLS + f] = acc;
}

extern "C" void kernel_launch(void* const* d_in, const int* in_sizes, int n_in,
                              void* d_out, int out_size, void* d_ws, size_t ws_size,
                              hipStream_t stream)
{
    const float* x      = (const float*)d_in[0];
    const int*   vertex = (const int*)  d_in[1];
    const int*   edges  = (const int*)  d_in[2];
    const float* W0     = (const float*)d_in[3];
    const float* b0     = (const float*)d_in[4];
    const float* Ws     = (const float*)d_in[5];
    const float* Wout   = (const float*)d_in[6];
    const float* bout   = (const float*)d_in[7];
    float* out = (float*)d_out;

    char* ws = (char*)d_ws;
    unsigned long long* binned = (unsigned long long*)ws; ws += (size_t)NNZ_C * 8;
    float*  X0    = (float*)ws;   ws += (size_t)N_NODES * HID * 4;
    __half* Xh    = (__half*)ws;  ws += (size_t)N_NODES * HID * 2;
    __half* Xeh   = (__half*)ws;  ws += (size_t)N_EDGES * HID * 2;
    int*   adj_e  = (int*)ws;     ws += (size_t)NNZ_C * 4;
    int*   adj_v  = (int*)ws;     ws += (size_t)NNZ_C * 4;
    int*   off_e  = (int*)ws;     ws += (size_t)(N_EDGES + 1) * 4;
    int*   off_v  = (int*)ws;     ws += (size_t)(N_NODES + 1) * 4;
    int*   cnt_e  = (int*)ws;     ws += (size_t)N_EDGES * 4;   // cnt_e,cnt_v contiguous
    int*   cnt_v  = (int*)ws;     ws += (size_t)N_NODES * 4;
    float* inv_e  = (float*)ws;   ws += (size_t)N_EDGES * 4;
    float* inv_v  = (float*)ws;   ws += (size_t)N_NODES * 4;
    int*   cur_be = (int*)ws;     ws += (size_t)NB_E * 4;
    int*   cur_bv = (int*)ws;     ws += (size_t)NB_V * 4;

    // ---- CSR build ----
    hipMemsetAsync(cnt_e, 0, (size_t)(N_EDGES + N_NODES) * 4, stream);
    degrees<<<(NNZ_C + 255) / 256, 256, 0, stream>>>(vertex, edges, cnt_e, cnt_v);
    scan_kernel<<<1, 1024, 0, stream>>>(cnt_e, off_e, inv_e, N_EDGES);
    scan_kernel<<<1, 1024, 0, stream>>>(cnt_v, off_v, inv_v, N_NODES);
    init_cur<<<1, 512, 0, stream>>>(off_e, ESHIFT, NB_E, cur_be);
    init_cur<<<1, 512, 0, stream>>>(off_v, VSHIFT, NB_V, cur_bv);

    const int p1_grid = (NNZ_C + 4095) / 4096;
    bin_pass1<<<p1_grid, 256, 0, stream>>>(edges, vertex, ESHIFT, NB_E, cur_be, binned);
    bin_pass2<<<NB_E, 256, 0, stream>>>(binned, off_e, ESHIFT, N_EDGES, adj_e);
    bin_pass1<<<p1_grid, 256, 0, stream>>>(vertex, edges, VSHIFT, NB_V, cur_bv, binned);
    bin_pass2<<<NB_V, 256, 0, stream>>>(binned, off_v, VSHIFT, N_NODES, adj_v);

    input_gemm<<<(N_NODES + 3) / 4, 256, 0, stream>>>(x, W0, b0, X0, Xh);

    for (int l = 0; l < NLAYER; ++l) {
        float beta = logf(0.5f / (float)(l + 1) + 1.0f);
        edge_gather<<<(N_EDGES * 64 + 255) / 256, 256, 0, stream>>>(Xh, adj_e, off_e, inv_e, Xeh);
        node_fused<<<(N_NODES + 3) / 4, 256, 0, stream>>>(
            Xeh, adj_v, off_v, inv_v, X0, Ws + (size_t)l * HID * HID, Xh, beta);
    }

    out_gemm<<<(N_NODES + 3) / 4, 256, 0, stream>>>(Xh, Wout, bout, out);
}

// Round 4
// 628.697 us; speedup vs baseline: 3.3406x; 1.2106x over previous
//
#include <hip/hip_runtime.h>
#include <hip/hip_fp16.h>
#include <math.h>

#define N_NODES 50000
#define N_EDGES 20000
#define NNZ_C   1000000
#define F_IN    128
#define HID     64
#define NCLS    40
#define NLAYER  4
#define ALPHA   0.1f

#define ESHIFT  6                        // 64 edges / bucket
#define VSHIFT  7                        // 128 vertices / bucket
#define NB_E    ((N_EDGES + 63) / 64)    // 313
#define NB_V    ((N_NODES + 127) / 128)  // 391
#define MAXNB   391

#define M_TOT   (N_EDGES + N_NODES)      // 70000
#define SCHUNK  1024
#define NSBLK   ((M_TOT + SCHUNK - 1) / SCHUNK)   // 69

// ---------------- X0 = relu(x @ W0 + b0) fp32; Xh = fp16 copy ----------------
__global__ __launch_bounds__(256) void input_gemm(
    const float* __restrict__ x, const float* __restrict__ W0,
    const float* __restrict__ b0, float* __restrict__ X0, __half* __restrict__ Xh)
{
    __shared__ float w[F_IN * HID];          // 32 KB
    int tid = threadIdx.x;
    for (int i = tid; i < F_IN * HID; i += 256) w[i] = W0[i];
    __syncthreads();
    int row = blockIdx.x * 4 + (tid >> 6);
    int col = tid & 63;
    if (row >= N_NODES) return;
    const float4* xr4 = (const float4*)(x + (long long)row * F_IN);
    float acc = 0.f;
    #pragma unroll
    for (int k = 0; k < F_IN / 4; ++k) {
        float4 xv = xr4[k];
        acc += xv.x * w[(4 * k + 0) * HID + col];
        acc += xv.y * w[(4 * k + 1) * HID + col];
        acc += xv.z * w[(4 * k + 2) * HID + col];
        acc += xv.w * w[(4 * k + 3) * HID + col];
    }
    float v = acc + b0[col];
    v = v > 0.f ? v : 0.f;
    X0[row * HID + col] = v;
    Xh[row * HID + col] = __float2half(v);
}

// ---------------- degree histogram (int4) ----------------
__global__ __launch_bounds__(256) void degrees(
    const int* __restrict__ vertex, const int* __restrict__ edges,
    int* __restrict__ cnt_e, int* __restrict__ cnt_v)
{
    int i = (blockIdx.x * 256 + threadIdx.x) * 4;
    if (i >= NNZ_C) return;
    int4 e4 = *(const int4*)(edges + i);
    int4 v4 = *(const int4*)(vertex + i);
    atomicAdd(&cnt_e[e4.x], 1); atomicAdd(&cnt_e[e4.y], 1);
    atomicAdd(&cnt_e[e4.z], 1); atomicAdd(&cnt_e[e4.w], 1);
    atomicAdd(&cnt_v[v4.x], 1); atomicAdd(&cnt_v[v4.y], 1);
    atomicAdd(&cnt_v[v4.z], 1); atomicAdd(&cnt_v[v4.w], 1);
}

// ---------------- hierarchical scan over cnt_e || cnt_v ----------------
__global__ __launch_bounds__(256) void scan_phase1(
    const int* __restrict__ cnt, int* __restrict__ bsum)
{
    int b = blockIdx.x;
    int base = b * SCHUNK;
    int n = M_TOT - base; if (n > SCHUNK) n = SCHUNK;
    int tid = threadIdx.x;
    int s = 0;
    for (int i = tid; i < n; i += 256) s += cnt[base + i];
    #pragma unroll
    for (int o = 32; o > 0; o >>= 1) s += __shfl_xor(s, o, 64);
    __shared__ int wsum[4];
    if ((tid & 63) == 0) wsum[tid >> 6] = s;
    __syncthreads();
    if (tid == 0) bsum[b] = wsum[0] + wsum[1] + wsum[2] + wsum[3];
}

__global__ __launch_bounds__(128) void scan_phase2(
    const int* __restrict__ bsum, int* __restrict__ bbase,
    int* __restrict__ off_e, int* __restrict__ off_v)
{
    __shared__ int tmp[128];
    int tid = threadIdx.x;
    int v = (tid < NSBLK) ? bsum[tid] : 0;
    tmp[tid] = v;
    __syncthreads();
    for (int d = 1; d < 128; d <<= 1) {
        int t = (tid >= d) ? tmp[tid - d] : 0;
        __syncthreads();
        tmp[tid] += t;
        __syncthreads();
    }
    if (tid < NSBLK) bbase[tid] = tmp[tid] - v;   // exclusive
    if (tid == 0) { off_e[N_EDGES] = NNZ_C; off_v[N_NODES] = NNZ_C; }
}

__global__ __launch_bounds__(256) void scan_phase3(
    const int* __restrict__ cnt, const int* __restrict__ bbase,
    int* __restrict__ off_e, int* __restrict__ off_v,
    float* __restrict__ inv_e, float* __restrict__ inv_v)
{
    int b = blockIdx.x;
    int base0 = b * SCHUNK;
    int n = M_TOT - base0; if (n > SCHUNK) n = SCHUNK;
    int tid = threadIdx.x;
    int lane = tid & 63, wv = tid >> 6;
    int i0 = tid * 4;
    int c[4]; int s = 0;
    #pragma unroll
    for (int k = 0; k < 4; ++k) {
        int i = i0 + k;
        c[k] = (i < n) ? cnt[base0 + i] : 0;
        s += c[k];
    }
    int incl = s;
    #pragma unroll
    for (int o = 1; o < 64; o <<= 1) {
        int t = __shfl_up(incl, o, 64);
        if (lane >= o) incl += t;
    }
    __shared__ int wsum[4];
    if (lane == 63) wsum[wv] = incl;
    __syncthreads();
    int wbase = 0;
    for (int k = 0; k < wv; ++k) wbase += wsum[k];
    int excl = wbase + incl - s + bbase[b];
    #pragma unroll
    for (int k = 0; k < 4; ++k) {
        int i = i0 + k;
        if (i < n) {
            int gi = base0 + i;
            float iv = 1.0f / fmaxf((float)c[k], 1.0f);
            if (gi < N_EDGES) { off_e[gi] = excl;         inv_e[gi] = iv; }
            else              { off_v[gi - N_EDGES] = excl - NNZ_C; inv_v[gi - N_EDGES] = iv; }
            excl += c[k];
        }
    }
}

__global__ void init_cur(const int* __restrict__ off, int shift, int nb,
                         int* __restrict__ cur)
{
    int b = blockIdx.x * blockDim.x + threadIdx.x;
    if (b < nb) cur[b] = off[b << shift];
}

// ---------------- pass 1: bin pairs into coarse buckets ----------------
__global__ __launch_bounds__(256) void bin_pass1(
    const int* __restrict__ keys, const int* __restrict__ vals,
    int shift, int nb, int* __restrict__ cur,
    unsigned long long* __restrict__ binned)
{
    __shared__ int hist[MAXNB];
    __shared__ int base[MAXNB];
    int tid = threadIdx.x;
    int blk = blockIdx.x * 4096;
    int nh = NNZ_C - blk; if (nh > 4096) nh = 4096;
    for (int i = tid; i < nb; i += 256) hist[i] = 0;
    __syncthreads();
    for (int i = tid; i < nh; i += 256)
        atomicAdd(&hist[keys[blk + i] >> shift], 1);
    __syncthreads();
    for (int i = tid; i < nb; i += 256) {
        int c = hist[i];
        base[i] = c ? atomicAdd(&cur[i], c) : 0;
        hist[i] = 0;
    }
    __syncthreads();
    for (int i = tid; i < nh; i += 256) {
        int k = keys[blk + i], v = vals[blk + i];
        int bkt = k >> shift;
        int r = atomicAdd(&hist[bkt], 1);
        binned[base[bkt] + r] = ((unsigned long long)(unsigned)k << 32) | (unsigned)v;
    }
}

// ---------------- pass 2: one block per bucket, finish counting sort ----------------
__global__ __launch_bounds__(256) void bin_pass2(
    const unsigned long long* __restrict__ binned, const int* __restrict__ off,
    int shift, int nkeys, int* __restrict__ adj)
{
    __shared__ int cur[128];
    int b  = blockIdx.x;
    int k0 = b << shift;
    int bs = 1 << shift;
    int kn = nkeys - k0; if (kn > bs) kn = bs;
    for (int i = threadIdx.x; i < kn; i += 256) cur[i] = off[k0 + i];
    __syncthreads();
    int beg = off[k0];
    int end = off[k0 + kn];
    for (int j = beg + threadIdx.x; j < end; j += 256) {
        unsigned long long p = binned[j];
        int k = (int)(p >> 32);
        int v = (int)(p & 0xffffffffULL);
        int pos = atomicAdd(&cur[k - k0], 1);
        adj[pos] = v;
    }
}

// ---- gather core: 8 lanes x 16B per row, 8 rows per wave step --------------
// returns acc[8]: lane (g=lane>>3, c=lane&7) accumulates features c*8+q over
// rows where (row_slot == g); caller reduces over g with shfl_xor 8/16/32.
__device__ __forceinline__ void gather_rows(
    const __half* __restrict__ src, const int* __restrict__ adj,
    int beg, int end, int lane, float acc[8])
{
    int g = lane >> 3, c = lane & 7;
    for (int j = beg; j < end; j += 64) {
        int nj = end - j; if (nj > 64) nj = 64;
        int myidx = (lane < nj) ? adj[j + lane] : 0;
        for (int s = 0; (s << 3) < nj; ++s) {
            int r = (s << 3) + g;
            int srcl = r < nj ? r : 0;
            int idx = __shfl(myidx, srcl);          // all lanes active
            if (r < nj) {
                uint4 raw = ((const uint4*)(src + (size_t)idx * HID))[c];
                union { uint4 u; __half2 h[4]; } U; U.u = raw;
                float2 f0 = __half22float2(U.h[0]);
                float2 f1 = __half22float2(U.h[1]);
                float2 f2 = __half22float2(U.h[2]);
                float2 f3 = __half22float2(U.h[3]);
                acc[0] += f0.x; acc[1] += f0.y;
                acc[2] += f1.x; acc[3] += f1.y;
                acc[4] += f2.x; acc[5] += f2.y;
                acc[6] += f3.x; acc[7] += f3.y;
            }
        }
    }
    #pragma unroll
    for (int q = 0; q < 8; ++q) {
        acc[q] += __shfl_xor(acc[q], 8);
        acc[q] += __shfl_xor(acc[q], 16);
        acc[q] += __shfl_xor(acc[q], 32);
    }
}

// ---------------- Xe[e] = inv_e[e] * sum_{v in adj_e[e]} X[v] ----------------
__global__ __launch_bounds__(256) void edge_gather(
    const __half* __restrict__ Xh, const int* __restrict__ adj_e,
    const int* __restrict__ off_e, const float* __restrict__ inv_e,
    __half* __restrict__ Xeh)
{
    int wid  = blockIdx.x * 4 + (threadIdx.x >> 6);   // edge id (grid exact)
    int lane = threadIdx.x & 63;
    float acc[8] = {0.f,0.f,0.f,0.f,0.f,0.f,0.f,0.f};
    gather_rows(Xh, adj_e, off_e[wid], off_e[wid + 1], lane, acc);
    if ((lane >> 3) == 0) {                            // lanes 0..7, c = lane
        float sc = inv_e[wid];
        union { uint4 u; __half2 h[4]; } O;
        O.h[0] = __floats2half2_rn(acc[0] * sc, acc[1] * sc);
        O.h[1] = __floats2half2_rn(acc[2] * sc, acc[3] * sc);
        O.h[2] = __floats2half2_rn(acc[4] * sc, acc[5] * sc);
        O.h[3] = __floats2half2_rn(acc[6] * sc, acc[7] * sc);
        ((uint4*)(Xeh + (size_t)wid * HID))[lane] = O.u;
    }
}

// ---------------- node fused: gather-mean -> l2norm -> alpha-mix -> (1-b)I+b*Ws -> relu ----------------
__global__ __launch_bounds__(256) void node_fused(
    const __half* __restrict__ Xeh, const int* __restrict__ adj_v,
    const int* __restrict__ off_v, const float* __restrict__ inv_v,
    const float* __restrict__ X0, const float* __restrict__ Wl,
    __half* __restrict__ Xh, float beta)
{
    __shared__ float w[HID * HID];           // 16 KB
    __shared__ float xi[4][HID];
    int tid = threadIdx.x;
    for (int i = tid; i < HID * HID; i += 256) w[i] = Wl[i];
    __syncthreads();
    int wv   = tid >> 6;
    int row  = blockIdx.x * 4 + wv;          // grid exact: always < N_NODES
    int lane = tid & 63;
    float acc[8] = {0.f,0.f,0.f,0.f,0.f,0.f,0.f,0.f};
    gather_rows(Xeh, adj_v, off_v[row], off_v[row + 1], lane, acc);
    float scm = inv_v[row];
    if ((lane >> 3) == 0) {
        #pragma unroll
        for (int q = 0; q < 8; ++q) xi[wv][lane * 8 + q] = acc[q] * scm;
    }
    __syncthreads();
    float mean = xi[wv][lane];
    float s = mean * mean;
    #pragma unroll
    for (int o = 32; o > 0; o >>= 1) s += __shfl_xor(s, o, 64);
    float norm  = sqrtf(s);
    float scale = norm > 0.f ? 1.0f / norm : 0.f;
    float xif = (1.0f - ALPHA) * (mean * scale) + ALPHA * X0[row * HID + lane];
    float gacc = 0.f;
    #pragma unroll
    for (int k = 0; k < HID; ++k)
        gacc += __shfl(xif, k) * w[k * HID + lane];
    float y = (1.0f - beta) * xif + beta * gacc;
    Xh[row * HID + lane] = __float2half(y > 0.f ? y : 0.f);
}

// ---------------- out = X @ Wout + bout ----------------
__global__ __launch_bounds__(256) void out_gemm(
    const __half* __restrict__ Xh, const float* __restrict__ Wout,
    const float* __restrict__ bout, float* __restrict__ out)
{
    __shared__ float w[HID * NCLS];          // 10.2 KB
    __shared__ float xr[4][HID];
    int tid = threadIdx.x;
    for (int i = tid; i < HID * NCLS; i += 256) w[i] = Wout[i];
    int row = blockIdx.x * 4 + (tid >> 6);
    int f   = tid & 63;
    int wv  = tid >> 6;
    float xv = 0.f;
    if (row < N_NODES) xv = __half2float(Xh[row * HID + f]);
    xr[wv][f] = xv;
    __syncthreads();
    if (row >= N_NODES || f >= NCLS) return;
    float acc = bout[f];
    #pragma unroll
    for (int k = 0; k < HID; ++k) acc += xr[wv][k] * w[k * NCLS + f];
    out[row * NCLS + f] = acc;
}

extern "C" void kernel_launch(void* const* d_in, const int* in_sizes, int n_in,
                              void* d_out, int out_size, void* d_ws, size_t ws_size,
                              hipStream_t stream)
{
    const float* x      = (const float*)d_in[0];
    const int*   vertex = (const int*)  d_in[1];
    const int*   edges  = (const int*)  d_in[2];
    const float* W0     = (const float*)d_in[3];
    const float* b0     = (const float*)d_in[4];
    const float* Ws     = (const float*)d_in[5];
    const float* Wout   = (const float*)d_in[6];
    const float* bout   = (const float*)d_in[7];
    float* out = (float*)d_out;

    char* ws = (char*)d_ws;
    unsigned long long* binned = (unsigned long long*)ws; ws += (size_t)NNZ_C * 8;
    float*  X0    = (float*)ws;   ws += (size_t)N_NODES * HID * 4;
    __half* Xh    = (__half*)ws;  ws += (size_t)N_NODES * HID * 2;
    __half* Xeh   = (__half*)ws;  ws += (size_t)N_EDGES * HID * 2;
    int*   adj_e  = (int*)ws;     ws += (size_t)NNZ_C * 4;
    int*   adj_v  = (int*)ws;     ws += (size_t)NNZ_C * 4;
    int*   off_e  = (int*)ws;     ws += (size_t)(N_EDGES + 1) * 4;
    int*   off_v  = (int*)ws;     ws += (size_t)(N_NODES + 1) * 4;
    int*   cnt_e  = (int*)ws;     ws += (size_t)N_EDGES * 4;   // cnt_e,cnt_v contiguous
    int*   cnt_v  = (int*)ws;     ws += (size_t)N_NODES * 4;
    float* inv_e  = (float*)ws;   ws += (size_t)N_EDGES * 4;
    float* inv_v  = (float*)ws;   ws += (size_t)N_NODES * 4;
    int*   cur_be = (int*)ws;     ws += (size_t)NB_E * 4;
    int*   cur_bv = (int*)ws;     ws += (size_t)NB_V * 4;
    int*   bsum   = (int*)ws;     ws += 256 * 4;
    int*   bbase  = (int*)ws;     ws += 256 * 4;

    // ---- CSR build ----
    hipMemsetAsync(cnt_e, 0, (size_t)M_TOT * 4, stream);   // cnt_e || cnt_v
    degrees<<<(NNZ_C / 4 + 255) / 256, 256, 0, stream>>>(vertex, edges, cnt_e, cnt_v);
    scan_phase1<<<NSBLK, 256, 0, stream>>>(cnt_e, bsum);
    scan_phase2<<<1, 128, 0, stream>>>(bsum, bbase, off_e, off_v);
    scan_phase3<<<NSBLK, 256, 0, stream>>>(cnt_e, bbase, off_e, off_v, inv_e, inv_v);
    init_cur<<<1, 512, 0, stream>>>(off_e, ESHIFT, NB_E, cur_be);
    init_cur<<<1, 512, 0, stream>>>(off_v, VSHIFT, NB_V, cur_bv);

    const int p1_grid = (NNZ_C + 4095) / 4096;
    bin_pass1<<<p1_grid, 256, 0, stream>>>(edges, vertex, ESHIFT, NB_E, cur_be, binned);
    bin_pass2<<<NB_E, 256, 0, stream>>>(binned, off_e, ESHIFT, N_EDGES, adj_e);
    bin_pass1<<<p1_grid, 256, 0, stream>>>(vertex, edges, VSHIFT, NB_V, cur_bv, binned);
    bin_pass2<<<NB_V, 256, 0, stream>>>(binned, off_v, VSHIFT, N_NODES, adj_v);

    input_gemm<<<(N_NODES + 3) / 4, 256, 0, stream>>>(x, W0, b0, X0, Xh);

    for (int l = 0; l < NLAYER; ++l) {
        float beta = logf(0.5f / (float)(l + 1) + 1.0f);
        edge_gather<<<N_EDGES / 4, 256, 0, stream>>>(Xh, adj_e, off_e, inv_e, Xeh);
        node_fused<<<N_NODES / 4, 256, 0, stream>>>(
            Xeh, adj_v, off_v, inv_v, X0, Ws + (size_t)l * HID * HID, Xh, beta);
    }

    out_gemm<<<(N_NODES + 3) / 4, 256, 0, stream>>>(Xh, Wout, bout, out);
}

// Round 5
// 541.983 us; speedup vs baseline: 3.8751x; 1.1600x over previous
//
#include <hip/hip_runtime.h>
#include <hip/hip_fp16.h>
#include <math.h>

#define N_NODES 50000
#define N_EDGES 20000
#define NNZ_C   1000000
#define F_IN    128
#define HID     64
#define NCLS    40
#define NLAYER  4
#define ALPHA   0.1f

#define ESHIFT  6                        // 64 edges / bucket
#define VSHIFT  7                        // 128 vertices / bucket
#define NB_E    ((N_EDGES + 63) / 64)    // 313
#define NB_V    ((N_NODES + 127) / 128)  // 391
#define NB_TOT  (NB_E + NB_V)            // 704
#define MAXNB   391

// ---------------- X0 = relu(x @ W0 + b0) fp32; Xh = fp16 copy ----------------
__global__ __launch_bounds__(256) void input_gemm(
    const float* __restrict__ x, const float* __restrict__ W0,
    const float* __restrict__ b0, float* __restrict__ X0, __half* __restrict__ Xh)
{
    __shared__ float w[F_IN * HID];          // 32 KB
    int tid = threadIdx.x;
    for (int i = tid; i < F_IN * HID; i += 256) w[i] = W0[i];
    __syncthreads();
    int row = blockIdx.x * 4 + (tid >> 6);
    int col = tid & 63;
    if (row >= N_NODES) return;
    const float4* xr4 = (const float4*)(x + (long long)row * F_IN);
    float acc = 0.f;
    #pragma unroll
    for (int k = 0; k < F_IN / 4; ++k) {
        float4 xv = xr4[k];
        acc += xv.x * w[(4 * k + 0) * HID + col];
        acc += xv.y * w[(4 * k + 1) * HID + col];
        acc += xv.z * w[(4 * k + 2) * HID + col];
        acc += xv.w * w[(4 * k + 3) * HID + col];
    }
    float v = acc + b0[col];
    v = v > 0.f ? v : 0.f;
    X0[row * HID + col] = v;
    Xh[row * HID + col] = __float2half(v);
}

// ---------------- per-block LDS bucket histogram (704 coarse buckets) ----------------
__global__ __launch_bounds__(256) void bucket_hist(
    const int* __restrict__ vertex, const int* __restrict__ edges,
    int* __restrict__ gcnt)
{
    __shared__ int h[NB_TOT];
    int tid = threadIdx.x;
    for (int i = tid; i < NB_TOT; i += 256) h[i] = 0;
    __syncthreads();
    int base = blockIdx.x * 4096;
    int n = NNZ_C - base; if (n > 4096) n = 4096;   // always multiple of 4
    for (int i = tid * 4; i < n; i += 1024) {
        int4 e4 = *(const int4*)(edges  + base + i);
        int4 v4 = *(const int4*)(vertex + base + i);
        atomicAdd(&h[e4.x >> ESHIFT], 1);
        atomicAdd(&h[e4.y >> ESHIFT], 1);
        atomicAdd(&h[e4.z >> ESHIFT], 1);
        atomicAdd(&h[e4.w >> ESHIFT], 1);
        atomicAdd(&h[NB_E + (v4.x >> VSHIFT)], 1);
        atomicAdd(&h[NB_E + (v4.y >> VSHIFT)], 1);
        atomicAdd(&h[NB_E + (v4.z >> VSHIFT)], 1);
        atomicAdd(&h[NB_E + (v4.w >> VSHIFT)], 1);
    }
    __syncthreads();
    for (int i = tid; i < NB_TOT; i += 256)
        if (h[i]) atomicAdd(&gcnt[i], h[i]);
}

// ---------------- scan 704 bucket counts -> bucket offsets + cursors ----------------
__global__ __launch_bounds__(1024) void bucket_scan(
    const int* __restrict__ gcnt, int* __restrict__ boff_e,
    int* __restrict__ boff_v, int* __restrict__ curb)
{
    __shared__ int tmp[1024];
    int tid = threadIdx.x;
    int v = (tid < NB_TOT) ? gcnt[tid] : 0;
    tmp[tid] = v;
    __syncthreads();
    for (int d = 1; d < 1024; d <<= 1) {
        int t = (tid >= d) ? tmp[tid - d] : 0;
        __syncthreads();
        tmp[tid] += t;
        __syncthreads();
    }
    if (tid < NB_TOT) {
        int excl = tmp[tid] - v;
        int off = (tid < NB_E) ? excl : excl - NNZ_C;  // v-part is 0-based too
        if (tid < NB_E) boff_e[tid] = off; else boff_v[tid - NB_E] = off;
        curb[tid] = off;
    }
    if (tid == 0) { boff_e[NB_E] = NNZ_C; boff_v[NB_V] = NNZ_C; }
}

// ---------------- pass 1: bin pairs into coarse buckets ----------------
__global__ __launch_bounds__(256) void bin_pass1(
    const int* __restrict__ keys, const int* __restrict__ vals,
    int shift, int nb, int* __restrict__ cur,
    unsigned long long* __restrict__ binned)
{
    __shared__ int hist[MAXNB];
    __shared__ int base[MAXNB];
    int tid = threadIdx.x;
    int blk = blockIdx.x * 4096;
    int nh = NNZ_C - blk; if (nh > 4096) nh = 4096;
    for (int i = tid; i < nb; i += 256) hist[i] = 0;
    __syncthreads();
    for (int i = tid; i < nh; i += 256)
        atomicAdd(&hist[keys[blk + i] >> shift], 1);
    __syncthreads();
    for (int i = tid; i < nb; i += 256) {
        int c = hist[i];
        base[i] = c ? atomicAdd(&cur[i], c) : 0;
        hist[i] = 0;
    }
    __syncthreads();
    for (int i = tid; i < nh; i += 256) {
        int k = keys[blk + i], v = vals[blk + i];
        int bkt = k >> shift;
        int r = atomicAdd(&hist[bkt], 1);
        binned[base[bkt] + r] = ((unsigned long long)(unsigned)k << 32) | (unsigned)v;
    }
}

// ---------------- pass 2: per bucket -> local count/scan, write off/inv, place adj ----------------
__global__ __launch_bounds__(256) void bin_pass2f(
    const unsigned long long* __restrict__ binned, const int* __restrict__ boff,
    int shift, int nkeys, int* __restrict__ off, float* __restrict__ inv,
    int* __restrict__ adj)
{
    __shared__ int lcnt[128];
    __shared__ int ts[128];
    __shared__ int lcur[128];
    int b  = blockIdx.x;
    int k0 = b << shift;
    int bs = 1 << shift;
    int kn = nkeys - k0; if (kn > bs) kn = bs;
    int tid = threadIdx.x;
    if (tid < 128) lcnt[tid] = 0;
    __syncthreads();
    int beg = boff[b], end = boff[b + 1];
    for (int j = beg + tid; j < end; j += 256)
        atomicAdd(&lcnt[(int)(binned[j] >> 32) - k0], 1);
    __syncthreads();
    int c = 0;
    if (tid < 128) { c = lcnt[tid]; ts[tid] = c; }
    __syncthreads();
    #pragma unroll
    for (int d = 1; d < 128; d <<= 1) {
        int t = 0;
        if (tid < 128 && tid >= d) t = ts[tid - d];
        __syncthreads();
        if (tid < 128) ts[tid] += t;
        __syncthreads();
    }
    if (tid < kn) {
        int pos = beg + ts[tid] - c;     // bucket base + local exclusive prefix
        off[k0 + tid] = pos;
        inv[k0 + tid] = 1.0f / fmaxf((float)c, 1.0f);
        lcur[tid] = pos;
    }
    if (b == 0 && tid == 0) off[nkeys] = NNZ_C;
    __syncthreads();
    for (int j = beg + tid; j < end; j += 256) {
        unsigned long long p = binned[j];
        int k = (int)(p >> 32) - k0;
        int v = (int)(p & 0xffffffffULL);
        adj[atomicAdd(&lcur[k], 1)] = v;
    }
}

// ---- gather core: 8 lanes x 16B per row, 8 rows per wave step --------------
__device__ __forceinline__ void gather_rows(
    const __half* __restrict__ src, const int* __restrict__ adj,
    int beg, int end, int lane, float acc[8])
{
    int g = lane >> 3, c = lane & 7;
    for (int j = beg; j < end; j += 64) {
        int nj = end - j; if (nj > 64) nj = 64;
        int myidx = (lane < nj) ? adj[j + lane] : 0;
        for (int s = 0; (s << 3) < nj; ++s) {
            int r = (s << 3) + g;
            int srcl = r < nj ? r : 0;
            int idx = __shfl(myidx, srcl);          // all lanes active
            if (r < nj) {
                uint4 raw = ((const uint4*)(src + (size_t)idx * HID))[c];
                union { uint4 u; __half2 h[4]; } U; U.u = raw;
                float2 f0 = __half22float2(U.h[0]);
                float2 f1 = __half22float2(U.h[1]);
                float2 f2 = __half22float2(U.h[2]);
                float2 f3 = __half22float2(U.h[3]);
                acc[0] += f0.x; acc[1] += f0.y;
                acc[2] += f1.x; acc[3] += f1.y;
                acc[4] += f2.x; acc[5] += f2.y;
                acc[6] += f3.x; acc[7] += f3.y;
            }
        }
    }
    #pragma unroll
    for (int q = 0; q < 8; ++q) {
        acc[q] += __shfl_xor(acc[q], 8);
        acc[q] += __shfl_xor(acc[q], 16);
        acc[q] += __shfl_xor(acc[q], 32);
    }
}

// ---------------- Xe[e] = inv_e[e] * sum_{v in adj_e[e]} X[v] ----------------
__global__ __launch_bounds__(256) void edge_gather(
    const __half* __restrict__ Xh, const int* __restrict__ adj_e,
    const int* __restrict__ off_e, const float* __restrict__ inv_e,
    __half* __restrict__ Xeh)
{
    int wid  = blockIdx.x * 4 + (threadIdx.x >> 6);   // edge id (grid exact)
    int lane = threadIdx.x & 63;
    float acc[8] = {0.f,0.f,0.f,0.f,0.f,0.f,0.f,0.f};
    gather_rows(Xh, adj_e, off_e[wid], off_e[wid + 1], lane, acc);
    if ((lane >> 3) == 0) {                            // lanes 0..7, c = lane
        float sc = inv_e[wid];
        union { uint4 u; __half2 h[4]; } O;
        O.h[0] = __floats2half2_rn(acc[0] * sc, acc[1] * sc);
        O.h[1] = __floats2half2_rn(acc[2] * sc, acc[3] * sc);
        O.h[2] = __floats2half2_rn(acc[4] * sc, acc[5] * sc);
        O.h[3] = __floats2half2_rn(acc[6] * sc, acc[7] * sc);
        ((uint4*)(Xeh + (size_t)wid * HID))[lane] = O.u;
    }
}

// ---------------- node fused: gather-mean -> l2norm -> alpha-mix -> (1-b)I+b*Ws -> relu ----------------
__global__ __launch_bounds__(256) void node_fused(
    const __half* __restrict__ Xeh, const int* __restrict__ adj_v,
    const int* __restrict__ off_v, const float* __restrict__ inv_v,
    const float* __restrict__ X0, const float* __restrict__ Wl,
    __half* __restrict__ Xh, float beta)
{
    __shared__ float w[HID * HID];           // 16 KB
    __shared__ float xi[4][HID];
    int tid = threadIdx.x;
    for (int i = tid; i < HID * HID; i += 256) w[i] = Wl[i];
    __syncthreads();
    int wv   = tid >> 6;
    int row  = blockIdx.x * 4 + wv;          // grid exact: always < N_NODES
    int lane = tid & 63;
    float acc[8] = {0.f,0.f,0.f,0.f,0.f,0.f,0.f,0.f};
    gather_rows(Xeh, adj_v, off_v[row], off_v[row + 1], lane, acc);
    float scm = inv_v[row];
    if ((lane >> 3) == 0) {
        #pragma unroll
        for (int q = 0; q < 8; ++q) xi[wv][lane * 8 + q] = acc[q] * scm;
    }
    __syncthreads();
    float mean = xi[wv][lane];
    float s = mean * mean;
    #pragma unroll
    for (int o = 32; o > 0; o >>= 1) s += __shfl_xor(s, o, 64);
    float norm  = sqrtf(s);
    float scale = norm > 0.f ? 1.0f / norm : 0.f;
    float xif = (1.0f - ALPHA) * (mean * scale) + ALPHA * X0[row * HID + lane];
    float gacc = 0.f;
    #pragma unroll
    for (int k = 0; k < HID; ++k)
        gacc += __shfl(xif, k) * w[k * HID + lane];
    float y = (1.0f - beta) * xif + beta * gacc;
    Xh[row * HID + lane] = __float2half(y > 0.f ? y : 0.f);
}

// ---------------- out = X @ Wout + bout ----------------
__global__ __launch_bounds__(256) void out_gemm(
    const __half* __restrict__ Xh, const float* __restrict__ Wout,
    const float* __restrict__ bout, float* __restrict__ out)
{
    __shared__ float w[HID * NCLS];          // 10.2 KB
    __shared__ float xr[4][HID];
    int tid = threadIdx.x;
    for (int i = tid; i < HID * NCLS; i += 256) w[i] = Wout[i];
    int row = blockIdx.x * 4 + (tid >> 6);
    int f   = tid & 63;
    int wv  = tid >> 6;
    float xv = 0.f;
    if (row < N_NODES) xv = __half2float(Xh[row * HID + f]);
    xr[wv][f] = xv;
    __syncthreads();
    if (row >= N_NODES || f >= NCLS) return;
    float acc = bout[f];
    #pragma unroll
    for (int k = 0; k < HID; ++k) acc += xr[wv][k] * w[k * NCLS + f];
    out[row * NCLS + f] = acc;
}

extern "C" void kernel_launch(void* const* d_in, const int* in_sizes, int n_in,
                              void* d_out, int out_size, void* d_ws, size_t ws_size,
                              hipStream_t stream)
{
    const float* x      = (const float*)d_in[0];
    const int*   vertex = (const int*)  d_in[1];
    const int*   edges  = (const int*)  d_in[2];
    const float* W0     = (const float*)d_in[3];
    const float* b0     = (const float*)d_in[4];
    const float* Ws     = (const float*)d_in[5];
    const float* Wout   = (const float*)d_in[6];
    const float* bout   = (const float*)d_in[7];
    float* out = (float*)d_out;

    char* ws = (char*)d_ws;
    unsigned long long* binned = (unsigned long long*)ws; ws += (size_t)NNZ_C * 8;
    float*  X0    = (float*)ws;   ws += (size_t)N_NODES * HID * 4;
    __half* Xh    = (__half*)ws;  ws += (size_t)N_NODES * HID * 2;
    __half* Xeh   = (__half*)ws;  ws += (size_t)N_EDGES * HID * 2;
    int*   adj_e  = (int*)ws;     ws += (size_t)NNZ_C * 4;
    int*   adj_v  = (int*)ws;     ws += (size_t)NNZ_C * 4;
    int*   off_e  = (int*)ws;     ws += (size_t)(N_EDGES + 1) * 4;
    int*   off_v  = (int*)ws;     ws += (size_t)(N_NODES + 1) * 4;
    float* inv_e  = (float*)ws;   ws += (size_t)N_EDGES * 4;
    float* inv_v  = (float*)ws;   ws += (size_t)N_NODES * 4;
    int*   gcnt   = (int*)ws;     ws += (size_t)NB_TOT * 4;
    int*   boff_e = (int*)ws;     ws += (size_t)(NB_E + 1) * 4;
    int*   boff_v = (int*)ws;     ws += (size_t)(NB_V + 1) * 4;
    int*   curb   = (int*)ws;     ws += (size_t)NB_TOT * 4;

    const int p1_grid = (NNZ_C + 4095) / 4096;   // 245

    // ---- CSR build (no global per-key histogram, no global scan) ----
    hipMemsetAsync(gcnt, 0, (size_t)NB_TOT * 4, stream);
    bucket_hist<<<p1_grid, 256, 0, stream>>>(vertex, edges, gcnt);
    bucket_scan<<<1, 1024, 0, stream>>>(gcnt, boff_e, boff_v, curb);

    bin_pass1<<<p1_grid, 256, 0, stream>>>(edges, vertex, ESHIFT, NB_E, curb, binned);
    bin_pass2f<<<NB_E, 256, 0, stream>>>(binned, boff_e, ESHIFT, N_EDGES, off_e, inv_e, adj_e);
    bin_pass1<<<p1_grid, 256, 0, stream>>>(vertex, edges, VSHIFT, NB_V, curb + NB_E, binned);
    bin_pass2f<<<NB_V, 256, 0, stream>>>(binned, boff_v, VSHIFT, N_NODES, off_v, inv_v, adj_v);

    input_gemm<<<(N_NODES + 3) / 4, 256, 0, stream>>>(x, W0, b0, X0, Xh);

    for (int l = 0; l < NLAYER; ++l) {
        float beta = logf(0.5f / (float)(l + 1) + 1.0f);
        edge_gather<<<N_EDGES / 4, 256, 0, stream>>>(Xh, adj_e, off_e, inv_e, Xeh);
        node_fused<<<N_NODES / 4, 256, 0, stream>>>(
            Xeh, adj_v, off_v, inv_v, X0, Ws + (size_t)l * HID * HID, Xh, beta);
    }

    out_gemm<<<(N_NODES + 3) / 4, 256, 0, stream>>>(Xh, Wout, bout, out);
}

// Round 6
// 366.082 us; speedup vs baseline: 5.7370x; 1.4805x over previous
//
#include <hip/hip_runtime.h>
#include <hip/hip_fp16.h>
#include <math.h>

#define N_NODES 50000
#define N_EDGES 20000
#define NNZ_C   1000000
#define F_IN    128
#define HID     64
#define NCLS    40
#define NLAYER  4
#define ALPHA   0.1f

#define ESHIFT  6                        // 64 edges / bucket
#define VSHIFT  7                        // 128 vertices / bucket
#define NB_E    ((N_EDGES + 63) / 64)    // 313
#define NB_V    ((N_NODES + 127) / 128)  // 391
#define NB_TOT  (NB_E + NB_V)            // 704
#define MAXNB   391

typedef _Float16 f16x8 __attribute__((ext_vector_type(8)));
typedef float    f32x4 __attribute__((ext_vector_type(4)));

// ---------------- X0 = relu(x @ W0 + b0) fp32; Xh = fp16 copy ----------------
__global__ __launch_bounds__(256) void input_gemm(
    const float* __restrict__ x, const float* __restrict__ W0,
    const float* __restrict__ b0, float* __restrict__ X0, __half* __restrict__ Xh)
{
    __shared__ float w[F_IN * HID];          // 32 KB
    int tid = threadIdx.x;
    for (int i = tid; i < F_IN * HID; i += 256) w[i] = W0[i];
    __syncthreads();
    int row = blockIdx.x * 4 + (tid >> 6);
    int col = tid & 63;
    if (row >= N_NODES) return;
    const float4* xr4 = (const float4*)(x + (long long)row * F_IN);
    float acc = 0.f;
    #pragma unroll
    for (int k = 0; k < F_IN / 4; ++k) {
        float4 xv = xr4[k];
        acc += xv.x * w[(4 * k + 0) * HID + col];
        acc += xv.y * w[(4 * k + 1) * HID + col];
        acc += xv.z * w[(4 * k + 2) * HID + col];
        acc += xv.w * w[(4 * k + 3) * HID + col];
    }
    float v = acc + b0[col];
    v = v > 0.f ? v : 0.f;
    X0[row * HID + col] = v;
    Xh[row * HID + col] = __float2half(v);
}

// ---------------- W'[l] = (1-beta_l) I + beta_l Ws[l], fp16 ----------------
__global__ __launch_bounds__(256) void make_wp(
    const float* __restrict__ Ws, _Float16* __restrict__ Wp,
    float be0, float be1, float be2, float be3)
{
    int l = blockIdx.x;
    float beta = (l == 0) ? be0 : (l == 1) ? be1 : (l == 2) ? be2 : be3;
    for (int i = threadIdx.x; i < HID * HID; i += 256) {
        int k = i >> 6, n = i & 63;
        float v = beta * Ws[l * HID * HID + i] + ((k == n) ? (1.f - beta) : 0.f);
        Wp[l * HID * HID + i] = (_Float16)v;
    }
}

// ---------------- per-block LDS bucket histogram (704 coarse buckets) ----------------
__global__ __launch_bounds__(256) void bucket_hist(
    const int* __restrict__ vertex, const int* __restrict__ edges,
    int* __restrict__ gcnt)
{
    __shared__ int h[NB_TOT];
    int tid = threadIdx.x;
    for (int i = tid; i < NB_TOT; i += 256) h[i] = 0;
    __syncthreads();
    int base = blockIdx.x * 4096;
    int n = NNZ_C - base; if (n > 4096) n = 4096;   // always multiple of 4
    for (int i = tid * 4; i < n; i += 1024) {
        int4 e4 = *(const int4*)(edges  + base + i);
        int4 v4 = *(const int4*)(vertex + base + i);
        atomicAdd(&h[e4.x >> ESHIFT], 1);
        atomicAdd(&h[e4.y >> ESHIFT], 1);
        atomicAdd(&h[e4.z >> ESHIFT], 1);
        atomicAdd(&h[e4.w >> ESHIFT], 1);
        atomicAdd(&h[NB_E + (v4.x >> VSHIFT)], 1);
        atomicAdd(&h[NB_E + (v4.y >> VSHIFT)], 1);
        atomicAdd(&h[NB_E + (v4.z >> VSHIFT)], 1);
        atomicAdd(&h[NB_E + (v4.w >> VSHIFT)], 1);
    }
    __syncthreads();
    for (int i = tid; i < NB_TOT; i += 256)
        if (h[i]) atomicAdd(&gcnt[i], h[i]);
}

// ---------------- scan 704 bucket counts -> bucket offsets + cursors ----------------
__global__ __launch_bounds__(1024) void bucket_scan(
    const int* __restrict__ gcnt, int* __restrict__ boff_e,
    int* __restrict__ boff_v, int* __restrict__ curb)
{
    __shared__ int tmp[1024];
    int tid = threadIdx.x;
    int v = (tid < NB_TOT) ? gcnt[tid] : 0;
    tmp[tid] = v;
    __syncthreads();
    for (int d = 1; d < 1024; d <<= 1) {
        int t = (tid >= d) ? tmp[tid - d] : 0;
        __syncthreads();
        tmp[tid] += t;
        __syncthreads();
    }
    if (tid < NB_TOT) {
        int excl = tmp[tid] - v;
        int off = (tid < NB_E) ? excl : excl - NNZ_C;  // v-part is 0-based too
        if (tid < NB_E) boff_e[tid] = off; else boff_v[tid - NB_E] = off;
        curb[tid] = off;
    }
    if (tid == 0) { boff_e[NB_E] = NNZ_C; boff_v[NB_V] = NNZ_C; }
}

// ---------------- pass 1: bin pairs into coarse buckets ----------------
__global__ __launch_bounds__(256) void bin_pass1(
    const int* __restrict__ keys, const int* __restrict__ vals,
    int shift, int nb, int* __restrict__ cur,
    unsigned long long* __restrict__ binned)
{
    __shared__ int hist[MAXNB];
    __shared__ int base[MAXNB];
    int tid = threadIdx.x;
    int blk = blockIdx.x * 4096;
    int nh = NNZ_C - blk; if (nh > 4096) nh = 4096;
    for (int i = tid; i < nb; i += 256) hist[i] = 0;
    __syncthreads();
    for (int i = tid; i < nh; i += 256)
        atomicAdd(&hist[keys[blk + i] >> shift], 1);
    __syncthreads();
    for (int i = tid; i < nb; i += 256) {
        int c = hist[i];
        base[i] = c ? atomicAdd(&cur[i], c) : 0;
        hist[i] = 0;
    }
    __syncthreads();
    for (int i = tid; i < nh; i += 256) {
        int k = keys[blk + i], v = vals[blk + i];
        int bkt = k >> shift;
        int r = atomicAdd(&hist[bkt], 1);
        binned[base[bkt] + r] = ((unsigned long long)(unsigned)k << 32) | (unsigned)v;
    }
}

// ---------------- pass 2: per bucket -> local count/scan, write off/inv, place adj ----------------
__global__ __launch_bounds__(256) void bin_pass2f(
    const unsigned long long* __restrict__ binned, const int* __restrict__ boff,
    int shift, int nkeys, int* __restrict__ off, float* __restrict__ inv,
    int* __restrict__ adj)
{
    __shared__ int lcnt[128];
    __shared__ int ts[128];
    __shared__ int lcur[128];
    int b  = blockIdx.x;
    int k0 = b << shift;
    int bs = 1 << shift;
    int kn = nkeys - k0; if (kn > bs) kn = bs;
    int tid = threadIdx.x;
    if (tid < 128) lcnt[tid] = 0;
    __syncthreads();
    int beg = boff[b], end = boff[b + 1];
    for (int j = beg + tid; j < end; j += 256)
        atomicAdd(&lcnt[(int)(binned[j] >> 32) - k0], 1);
    __syncthreads();
    int c = 0;
    if (tid < 128) { c = lcnt[tid]; ts[tid] = c; }
    __syncthreads();
    #pragma unroll
    for (int d = 1; d < 128; d <<= 1) {
        int t = 0;
        if (tid < 128 && tid >= d) t = ts[tid - d];
        __syncthreads();
        if (tid < 128) ts[tid] += t;
        __syncthreads();
    }
    if (tid < kn) {
        int pos = beg + ts[tid] - c;     // bucket base + local exclusive prefix
        off[k0 + tid] = pos;
        inv[k0 + tid] = 1.0f / fmaxf((float)c, 1.0f);
        lcur[tid] = pos;
    }
    if (b == 0 && tid == 0) off[nkeys] = NNZ_C;
    __syncthreads();
    for (int j = beg + tid; j < end; j += 256) {
        unsigned long long p = binned[j];
        int k = (int)(p >> 32) - k0;
        int v = (int)(p & 0xffffffffULL);
        adj[atomicAdd(&lcur[k], 1)] = v;
    }
}

// ---- gather core: 8 lanes x 16B per row, 8 rows per wave step --------------
__device__ __forceinline__ void gather_rows(
    const __half* __restrict__ src, const int* __restrict__ adj,
    int beg, int end, int lane, float acc[8])
{
    int g = lane >> 3, c = lane & 7;
    for (int j = beg; j < end; j += 64) {
        int nj = end - j; if (nj > 64) nj = 64;
        int myidx = (lane < nj) ? adj[j + lane] : 0;
        for (int s = 0; (s << 3) < nj; ++s) {
            int r = (s << 3) + g;
            int srcl = r < nj ? r : 0;
            int idx = __shfl(myidx, srcl);          // all lanes active
            if (r < nj) {
                uint4 raw = ((const uint4*)(src + (size_t)idx * HID))[c];
                union { uint4 u; __half2 h[4]; } U; U.u = raw;
                float2 f0 = __half22float2(U.h[0]);
                float2 f1 = __half22float2(U.h[1]);
                float2 f2 = __half22float2(U.h[2]);
                float2 f3 = __half22float2(U.h[3]);
                acc[0] += f0.x; acc[1] += f0.y;
                acc[2] += f1.x; acc[3] += f1.y;
                acc[4] += f2.x; acc[5] += f2.y;
                acc[6] += f3.x; acc[7] += f3.y;
            }
        }
    }
    #pragma unroll
    for (int q = 0; q < 8; ++q) {
        acc[q] += __shfl_xor(acc[q], 8);
        acc[q] += __shfl_xor(acc[q], 16);
        acc[q] += __shfl_xor(acc[q], 32);
    }
}

// ---------------- Xe[e] = inv_e[e] * sum_{v in adj_e[e]} X[v] ----------------
__global__ __launch_bounds__(256) void edge_gather(
    const __half* __restrict__ Xh, const int* __restrict__ adj_e,
    const int* __restrict__ off_e, const float* __restrict__ inv_e,
    __half* __restrict__ Xeh)
{
    int wid  = blockIdx.x * 4 + (threadIdx.x >> 6);   // edge id (grid exact)
    int lane = threadIdx.x & 63;
    float acc[8] = {0.f,0.f,0.f,0.f,0.f,0.f,0.f,0.f};
    gather_rows(Xh, adj_e, off_e[wid], off_e[wid + 1], lane, acc);
    if ((lane >> 3) == 0) {                            // lanes 0..7, c = lane
        float sc = inv_e[wid];
        union { uint4 u; __half2 h[4]; } O;
        O.h[0] = __floats2half2_rn(acc[0] * sc, acc[1] * sc);
        O.h[1] = __floats2half2_rn(acc[2] * sc, acc[3] * sc);
        O.h[2] = __floats2half2_rn(acc[4] * sc, acc[5] * sc);
        O.h[3] = __floats2half2_rn(acc[6] * sc, acc[7] * sc);
        ((uint4*)(Xeh + (size_t)wid * HID))[lane] = O.u;
    }
}

// ---------------- node gather: mean -> l2norm -> alpha-mix -> Xi fp16 ----------------
__global__ __launch_bounds__(256) void node_gather(
    const __half* __restrict__ Xeh, const int* __restrict__ adj_v,
    const int* __restrict__ off_v, const float* __restrict__ inv_v,
    const float* __restrict__ X0, _Float16* __restrict__ Xi)
{
    int wv   = threadIdx.x >> 6;
    int row  = blockIdx.x * 4 + wv;          // grid exact: always < N_NODES
    int lane = threadIdx.x & 63;
    float acc[8] = {0.f,0.f,0.f,0.f,0.f,0.f,0.f,0.f};
    gather_rows(Xeh, adj_v, off_v[row], off_v[row + 1], lane, acc);
    float scm = inv_v[row];
    float m[8]; float s = 0.f;
    #pragma unroll
    for (int q = 0; q < 8; ++q) { m[q] = acc[q] * scm; s += m[q] * m[q]; }
    s += __shfl_xor(s, 1);
    s += __shfl_xor(s, 2);
    s += __shfl_xor(s, 4);                    // full row sum-of-squares, all lanes
    float norm  = sqrtf(s);
    float scale = norm > 0.f ? 1.0f / norm : 0.f;
    if ((lane >> 3) == 0) {                   // lanes 0..7, c = lane
        const float4* xp = (const float4*)(X0 + (size_t)row * HID + lane * 8);
        float4 xa = xp[0], xb = xp[1];
        float x0v[8] = {xa.x, xa.y, xa.z, xa.w, xb.x, xb.y, xb.z, xb.w};
        union { f16x8 v; uint4 u; } O;
        #pragma unroll
        for (int q = 0; q < 8; ++q)
            O.v[q] = (_Float16)((1.0f - ALPHA) * (m[q] * scale) + ALPHA * x0v[q]);
        *(uint4*)(Xi + (size_t)row * HID + lane * 8) = O.u;
    }
}

// ---------------- X = relu(Xi @ W') via MFMA 16x16x32 f16 ----------------
__global__ __launch_bounds__(256) void layer_gemm(
    const _Float16* __restrict__ Xi, const _Float16* __restrict__ Wp,
    _Float16* __restrict__ Xh)
{
    int lane = threadIdx.x & 63;
    int wv   = threadIdx.x >> 6;
    int r16  = lane & 15;
    int kgrp = lane >> 4;                    // 0..3
    // B fragments: 4 n-tiles x 2 k-halves, loaded once per wave
    f16x8 bf[4][2];
    #pragma unroll
    for (int n0 = 0; n0 < 4; ++n0)
        #pragma unroll
        for (int kh = 0; kh < 2; ++kh) {
            #pragma unroll
            for (int j = 0; j < 8; ++j)
                bf[n0][kh][j] = Wp[(kh * 32 + kgrp * 8 + j) * HID + n0 * 16 + r16];
        }
    int nwaves = gridDim.x * 4;
    for (int t = blockIdx.x * 4 + wv; t < N_NODES / 16; t += nwaves) {
        int row0 = t * 16;
        const _Float16* ap = Xi + (size_t)(row0 + r16) * HID + kgrp * 8;
        f16x8 a0 = *(const f16x8*)(ap);          // k = kgrp*8 .. +8
        f16x8 a1 = *(const f16x8*)(ap + 32);     // k += 32
        #pragma unroll
        for (int n0 = 0; n0 < 4; ++n0) {
            f32x4 acc = {0.f, 0.f, 0.f, 0.f};
            acc = __builtin_amdgcn_mfma_f32_16x16x32_f16(a0, bf[n0][0], acc, 0, 0, 0);
            acc = __builtin_amdgcn_mfma_f32_16x16x32_f16(a1, bf[n0][1], acc, 0, 0, 0);
            #pragma unroll
            for (int r = 0; r < 4; ++r) {
                float y = acc[r] > 0.f ? acc[r] : 0.f;
                Xh[(size_t)(row0 + kgrp * 4 + r) * HID + n0 * 16 + r16] = (_Float16)y;
            }
        }
    }
}

// ---------------- out = X @ Wout + bout ----------------
__global__ __launch_bounds__(256) void out_gemm(
    const __half* __restrict__ Xh, const float* __restrict__ Wout,
    const float* __restrict__ bout, float* __restrict__ out)
{
    __shared__ float w[HID * NCLS];          // 10.2 KB
    __shared__ float xr[4][HID];
    int tid = threadIdx.x;
    for (int i = tid; i < HID * NCLS; i += 256) w[i] = Wout[i];
    int row = blockIdx.x * 4 + (tid >> 6);
    int f   = tid & 63;
    int wv  = tid >> 6;
    float xv = 0.f;
    if (row < N_NODES) xv = __half2float(Xh[row * HID + f]);
    xr[wv][f] = xv;
    __syncthreads();
    if (row >= N_NODES || f >= NCLS) return;
    float acc = bout[f];
    #pragma unroll
    for (int k = 0; k < HID; ++k) acc += xr[wv][k] * w[k * NCLS + f];
    out[row * NCLS + f] = acc;
}

extern "C" void kernel_launch(void* const* d_in, const int* in_sizes, int n_in,
                              void* d_out, int out_size, void* d_ws, size_t ws_size,
                              hipStream_t stream)
{
    const float* x      = (const float*)d_in[0];
    const int*   vertex = (const int*)  d_in[1];
    const int*   edges  = (const int*)  d_in[2];
    const float* W0     = (const float*)d_in[3];
    const float* b0     = (const float*)d_in[4];
    const float* Ws     = (const float*)d_in[5];
    const float* Wout   = (const float*)d_in[6];
    const float* bout   = (const float*)d_in[7];
    float* out = (float*)d_out;

    char* ws = (char*)d_ws;
    unsigned long long* binned = (unsigned long long*)ws; ws += (size_t)NNZ_C * 8;
    float*     X0   = (float*)ws;     ws += (size_t)N_NODES * HID * 4;
    __half*    Xh   = (__half*)ws;    ws += (size_t)N_NODES * HID * 2;
    _Float16*  Xi   = (_Float16*)ws;  ws += (size_t)N_NODES * HID * 2;
    __half*    Xeh  = (__half*)ws;    ws += (size_t)N_EDGES * HID * 2;
    _Float16*  Wp   = (_Float16*)ws;  ws += (size_t)NLAYER * HID * HID * 2;
    int*   adj_e  = (int*)ws;     ws += (size_t)NNZ_C * 4;
    int*   adj_v  = (int*)ws;     ws += (size_t)NNZ_C * 4;
    int*   off_e  = (int*)ws;     ws += (size_t)(N_EDGES + 1) * 4;
    int*   off_v  = (int*)ws;     ws += (size_t)(N_NODES + 1) * 4;
    float* inv_e  = (float*)ws;   ws += (size_t)N_EDGES * 4;
    float* inv_v  = (float*)ws;   ws += (size_t)N_NODES * 4;
    int*   gcnt   = (int*)ws;     ws += (size_t)NB_TOT * 4;
    int*   boff_e = (int*)ws;     ws += (size_t)(NB_E + 1) * 4;
    int*   boff_v = (int*)ws;     ws += (size_t)(NB_V + 1) * 4;
    int*   curb   = (int*)ws;     ws += (size_t)NB_TOT * 4;

    const int p1_grid = (NNZ_C + 4095) / 4096;   // 245

    // ---- CSR build (no global per-key histogram, no global scan) ----
    hipMemsetAsync(gcnt, 0, (size_t)NB_TOT * 4, stream);
    bucket_hist<<<p1_grid, 256, 0, stream>>>(vertex, edges, gcnt);
    bucket_scan<<<1, 1024, 0, stream>>>(gcnt, boff_e, boff_v, curb);

    bin_pass1<<<p1_grid, 256, 0, stream>>>(edges, vertex, ESHIFT, NB_E, curb, binned);
    bin_pass2f<<<NB_E, 256, 0, stream>>>(binned, boff_e, ESHIFT, N_EDGES, off_e, inv_e, adj_e);
    bin_pass1<<<p1_grid, 256, 0, stream>>>(vertex, edges, VSHIFT, NB_V, curb + NB_E, binned);
    bin_pass2f<<<NB_V, 256, 0, stream>>>(binned, boff_v, VSHIFT, N_NODES, off_v, inv_v, adj_v);

    float be0 = logf(0.5f / 1.f + 1.0f);
    float be1 = logf(0.5f / 2.f + 1.0f);
    float be2 = logf(0.5f / 3.f + 1.0f);
    float be3 = logf(0.5f / 4.f + 1.0f);
    make_wp<<<NLAYER, 256, 0, stream>>>(Ws, Wp, be0, be1, be2, be3);

    input_gemm<<<(N_NODES + 3) / 4, 256, 0, stream>>>(x, W0, b0, X0, Xh);

    for (int l = 0; l < NLAYER; ++l) {
        edge_gather<<<N_EDGES / 4, 256, 0, stream>>>(Xh, adj_e, off_e, inv_e, Xeh);
        node_gather<<<N_NODES / 4, 256, 0, stream>>>(
            Xeh, adj_v, off_v, inv_v, X0, Xi);
        layer_gemm<<<391, 256, 0, stream>>>(Xi, Wp + (size_t)l * HID * HID,
                                            (_Float16*)Xh);
    }

    out_gemm<<<(N_NODES + 3) / 4, 256, 0, stream>>>(Xh, Wout, bout, out);
}

// Round 7
// 293.433 us; speedup vs baseline: 7.1574x; 1.2476x over previous
//
#include <hip/hip_runtime.h>
#include <hip/hip_fp16.h>
#include <math.h>

#define N_NODES 50000
#define N_EDGES 20000
#define NNZ_C   1000000
#define F_IN    128
#define HID     64
#define NCLS    40
#define NLAYER  4
#define ALPHA   0.1f

#define ESHIFT  6                        // 64 edges / bucket
#define VSHIFT  7                        // 128 vertices / bucket
#define NB_E    ((N_EDGES + 63) / 64)    // 313
#define NB_V    ((N_NODES + 127) / 128)  // 391
#define NB_TOT  (NB_E + NB_V)            // 704
#define MAXNB   391

typedef _Float16 f16x8 __attribute__((ext_vector_type(8)));
typedef float    f32x4 __attribute__((ext_vector_type(4)));

// ---------------- X0h = Xh = relu(x @ W0 + b0) via MFMA, fp16 out ----------------
__global__ __launch_bounds__(256) void input_gemm(
    const float* __restrict__ x, const float* __restrict__ W0,
    const float* __restrict__ b0, _Float16* __restrict__ X0h,
    _Float16* __restrict__ Xh)
{
    int lane = threadIdx.x & 63;
    int wv   = threadIdx.x >> 6;
    int r16  = lane & 15;
    int kgrp = lane >> 4;                    // 0..3
    // B fragments: 4 n-tiles x 4 k-chunks (K=128), fp32->fp16 once per wave
    f16x8 bf[4][4];
    #pragma unroll
    for (int n0 = 0; n0 < 4; ++n0)
        #pragma unroll
        for (int kh = 0; kh < 4; ++kh)
            #pragma unroll
            for (int j = 0; j < 8; ++j)
                bf[n0][kh][j] = (_Float16)W0[(kh * 32 + kgrp * 8 + j) * HID + n0 * 16 + r16];
    float bias[4];
    #pragma unroll
    for (int n0 = 0; n0 < 4; ++n0) bias[n0] = b0[n0 * 16 + r16];

    int nwaves = gridDim.x * 4;
    for (int t = blockIdx.x * 4 + wv; t < N_NODES / 16; t += nwaves) {
        int row0 = t * 16;
        const float* xp = x + (size_t)(row0 + r16) * F_IN + kgrp * 8;
        f16x8 a[4];
        #pragma unroll
        for (int kh = 0; kh < 4; ++kh) {
            float4 u0 = *(const float4*)(xp + kh * 32);
            float4 u1 = *(const float4*)(xp + kh * 32 + 4);
            a[kh][0] = (_Float16)u0.x; a[kh][1] = (_Float16)u0.y;
            a[kh][2] = (_Float16)u0.z; a[kh][3] = (_Float16)u0.w;
            a[kh][4] = (_Float16)u1.x; a[kh][5] = (_Float16)u1.y;
            a[kh][6] = (_Float16)u1.z; a[kh][7] = (_Float16)u1.w;
        }
        #pragma unroll
        for (int n0 = 0; n0 < 4; ++n0) {
            f32x4 acc = {0.f, 0.f, 0.f, 0.f};
            #pragma unroll
            for (int kh = 0; kh < 4; ++kh)
                acc = __builtin_amdgcn_mfma_f32_16x16x32_f16(a[kh], bf[n0][kh], acc, 0, 0, 0);
            #pragma unroll
            for (int r = 0; r < 4; ++r) {
                float y = acc[r] + bias[n0];
                y = y > 0.f ? y : 0.f;
                _Float16 h = (_Float16)y;
                size_t o = (size_t)(row0 + kgrp * 4 + r) * HID + n0 * 16 + r16;
                X0h[o] = h;
                Xh[o]  = h;
            }
        }
    }
}

// ---------------- W'[l] = (1-beta_l) I + beta_l Ws[l], fp16 ----------------
__global__ __launch_bounds__(256) void make_wp(
    const float* __restrict__ Ws, _Float16* __restrict__ Wp,
    float be0, float be1, float be2, float be3)
{
    int l = blockIdx.x;
    float beta = (l == 0) ? be0 : (l == 1) ? be1 : (l == 2) ? be2 : be3;
    for (int i = threadIdx.x; i < HID * HID; i += 256) {
        int k = i >> 6, n = i & 63;
        float v = beta * Ws[l * HID * HID + i] + ((k == n) ? (1.f - beta) : 0.f);
        Wp[l * HID * HID + i] = (_Float16)v;
    }
}

// ---------------- per-block LDS bucket histogram (704 coarse buckets) ----------------
__global__ __launch_bounds__(256) void bucket_hist(
    const int* __restrict__ vertex, const int* __restrict__ edges,
    int* __restrict__ gcnt)
{
    __shared__ int h[NB_TOT];
    int tid = threadIdx.x;
    for (int i = tid; i < NB_TOT; i += 256) h[i] = 0;
    __syncthreads();
    int base = blockIdx.x * 4096;
    int n = NNZ_C - base; if (n > 4096) n = 4096;   // always multiple of 4
    for (int i = tid * 4; i < n; i += 1024) {
        int4 e4 = *(const int4*)(edges  + base + i);
        int4 v4 = *(const int4*)(vertex + base + i);
        atomicAdd(&h[e4.x >> ESHIFT], 1);
        atomicAdd(&h[e4.y >> ESHIFT], 1);
        atomicAdd(&h[e4.z >> ESHIFT], 1);
        atomicAdd(&h[e4.w >> ESHIFT], 1);
        atomicAdd(&h[NB_E + (v4.x >> VSHIFT)], 1);
        atomicAdd(&h[NB_E + (v4.y >> VSHIFT)], 1);
        atomicAdd(&h[NB_E + (v4.z >> VSHIFT)], 1);
        atomicAdd(&h[NB_E + (v4.w >> VSHIFT)], 1);
    }
    __syncthreads();
    for (int i = tid; i < NB_TOT; i += 256)
        if (h[i]) atomicAdd(&gcnt[i], h[i]);
}

// ---------------- scan 704 bucket counts -> bucket offsets + cursors ----------------
__global__ __launch_bounds__(1024) void bucket_scan(
    const int* __restrict__ gcnt, int* __restrict__ boff_e,
    int* __restrict__ boff_v, int* __restrict__ curb)
{
    __shared__ int tmp[1024];
    int tid = threadIdx.x;
    int v = (tid < NB_TOT) ? gcnt[tid] : 0;
    tmp[tid] = v;
    __syncthreads();
    for (int d = 1; d < 1024; d <<= 1) {
        int t = (tid >= d) ? tmp[tid - d] : 0;
        __syncthreads();
        tmp[tid] += t;
        __syncthreads();
    }
    if (tid < NB_TOT) {
        int excl = tmp[tid] - v;
        int off = (tid < NB_E) ? excl : excl - NNZ_C;  // v-part is 0-based too
        if (tid < NB_E) boff_e[tid] = off; else boff_v[tid - NB_E] = off;
        curb[tid] = off;
    }
    if (tid == 0) { boff_e[NB_E] = NNZ_C; boff_v[NB_V] = NNZ_C; }
}

// ---------------- pass 1: bin pairs into coarse buckets ----------------
__global__ __launch_bounds__(256) void bin_pass1(
    const int* __restrict__ keys, const int* __restrict__ vals,
    int shift, int nb, int* __restrict__ cur,
    unsigned long long* __restrict__ binned)
{
    __shared__ int hist[MAXNB];
    __shared__ int base[MAXNB];
    int tid = threadIdx.x;
    int blk = blockIdx.x * 4096;
    int nh = NNZ_C - blk; if (nh > 4096) nh = 4096;
    for (int i = tid; i < nb; i += 256) hist[i] = 0;
    __syncthreads();
    for (int i = tid; i < nh; i += 256)
        atomicAdd(&hist[keys[blk + i] >> shift], 1);
    __syncthreads();
    for (int i = tid; i < nb; i += 256) {
        int c = hist[i];
        base[i] = c ? atomicAdd(&cur[i], c) : 0;
        hist[i] = 0;
    }
    __syncthreads();
    for (int i = tid; i < nh; i += 256) {
        int k = keys[blk + i], v = vals[blk + i];
        int bkt = k >> shift;
        int r = atomicAdd(&hist[bkt], 1);
        binned[base[bkt] + r] = ((unsigned long long)(unsigned)k << 32) | (unsigned)v;
    }
}

// ---------------- pass 2: per bucket -> local count/scan, write off/inv, place adj ----------------
__global__ __launch_bounds__(256) void bin_pass2f(
    const unsigned long long* __restrict__ binned, const int* __restrict__ boff,
    int shift, int nkeys, int* __restrict__ off, float* __restrict__ inv,
    int* __restrict__ adj)
{
    __shared__ int lcnt[128];
    __shared__ int ts[128];
    __shared__ int lcur[128];
    int b  = blockIdx.x;
    int k0 = b << shift;
    int bs = 1 << shift;
    int kn = nkeys - k0; if (kn > bs) kn = bs;
    int tid = threadIdx.x;
    if (tid < 128) lcnt[tid] = 0;
    __syncthreads();
    int beg = boff[b], end = boff[b + 1];
    for (int j = beg + tid; j < end; j += 256)
        atomicAdd(&lcnt[(int)(binned[j] >> 32) - k0], 1);
    __syncthreads();
    int c = 0;
    if (tid < 128) { c = lcnt[tid]; ts[tid] = c; }
    __syncthreads();
    #pragma unroll
    for (int d = 1; d < 128; d <<= 1) {
        int t = 0;
        if (tid < 128 && tid >= d) t = ts[tid - d];
        __syncthreads();
        if (tid < 128) ts[tid] += t;
        __syncthreads();
    }
    if (tid < kn) {
        int pos = beg + ts[tid] - c;     // bucket base + local exclusive prefix
        off[k0 + tid] = pos;
        inv[k0 + tid] = 1.0f / fmaxf((float)c, 1.0f);
        lcur[tid] = pos;
    }
    if (b == 0 && tid == 0) off[nkeys] = NNZ_C;
    __syncthreads();
    for (int j = beg + tid; j < end; j += 256) {
        unsigned long long p = binned[j];
        int k = (int)(p >> 32) - k0;
        int v = (int)(p & 0xffffffffULL);
        adj[atomicAdd(&lcur[k], 1)] = v;
    }
}

// ---- gather core: 8 lanes x 16B per row, 8 rows per wave step --------------
__device__ __forceinline__ void gather_rows(
    const __half* __restrict__ src, const int* __restrict__ adj,
    int beg, int end, int lane, float acc[8])
{
    int g = lane >> 3, c = lane & 7;
    for (int j = beg; j < end; j += 64) {
        int nj = end - j; if (nj > 64) nj = 64;
        int myidx = (lane < nj) ? adj[j + lane] : 0;
        for (int s = 0; (s << 3) < nj; ++s) {
            int r = (s << 3) + g;
            int srcl = r < nj ? r : 0;
            int idx = __shfl(myidx, srcl);          // all lanes active
            if (r < nj) {
                uint4 raw = ((const uint4*)(src + (size_t)idx * HID))[c];
                union { uint4 u; __half2 h[4]; } U; U.u = raw;
                float2 f0 = __half22float2(U.h[0]);
                float2 f1 = __half22float2(U.h[1]);
                float2 f2 = __half22float2(U.h[2]);
                float2 f3 = __half22float2(U.h[3]);
                acc[0] += f0.x; acc[1] += f0.y;
                acc[2] += f1.x; acc[3] += f1.y;
                acc[4] += f2.x; acc[5] += f2.y;
                acc[6] += f3.x; acc[7] += f3.y;
            }
        }
    }
    #pragma unroll
    for (int q = 0; q < 8; ++q) {
        acc[q] += __shfl_xor(acc[q], 8);
        acc[q] += __shfl_xor(acc[q], 16);
        acc[q] += __shfl_xor(acc[q], 32);
    }
}

// ---------------- Xe[e] = inv_e[e] * sum_{v in adj_e[e]} X[v] ----------------
__global__ __launch_bounds__(256) void edge_gather(
    const __half* __restrict__ Xh, const int* __restrict__ adj_e,
    const int* __restrict__ off_e, const float* __restrict__ inv_e,
    __half* __restrict__ Xeh)
{
    int wid  = blockIdx.x * 4 + (threadIdx.x >> 6);   // edge id (grid exact)
    int lane = threadIdx.x & 63;
    float acc[8] = {0.f,0.f,0.f,0.f,0.f,0.f,0.f,0.f};
    gather_rows(Xh, adj_e, off_e[wid], off_e[wid + 1], lane, acc);
    if ((lane >> 3) == 0) {                            // lanes 0..7, c = lane
        float sc = inv_e[wid];
        union { uint4 u; __half2 h[4]; } O;
        O.h[0] = __floats2half2_rn(acc[0] * sc, acc[1] * sc);
        O.h[1] = __floats2half2_rn(acc[2] * sc, acc[3] * sc);
        O.h[2] = __floats2half2_rn(acc[4] * sc, acc[5] * sc);
        O.h[3] = __floats2half2_rn(acc[6] * sc, acc[7] * sc);
        ((uint4*)(Xeh + (size_t)wid * HID))[lane] = O.u;
    }
}

// ---------------- node gather: mean -> l2norm -> alpha-mix -> Xi fp16 ----------------
__global__ __launch_bounds__(256) void node_gather(
    const __half* __restrict__ Xeh, const int* __restrict__ adj_v,
    const int* __restrict__ off_v, const float* __restrict__ inv_v,
    const _Float16* __restrict__ X0h, _Float16* __restrict__ Xi)
{
    int wv   = threadIdx.x >> 6;
    int row  = blockIdx.x * 4 + wv;          // grid exact: always < N_NODES
    int lane = threadIdx.x & 63;
    float acc[8] = {0.f,0.f,0.f,0.f,0.f,0.f,0.f,0.f};
    gather_rows(Xeh, adj_v, off_v[row], off_v[row + 1], lane, acc);
    float scm = inv_v[row];
    float m[8]; float s = 0.f;
    #pragma unroll
    for (int q = 0; q < 8; ++q) { m[q] = acc[q] * scm; s += m[q] * m[q]; }
    s += __shfl_xor(s, 1);
    s += __shfl_xor(s, 2);
    s += __shfl_xor(s, 4);                    // full row sum-of-squares, all lanes
    float norm  = sqrtf(s);
    float scale = norm > 0.f ? 1.0f / norm : 0.f;
    if ((lane >> 3) == 0) {                   // lanes 0..7, c = lane
        union { f16x8 v; uint4 u; } I;
        I.u = *(const uint4*)(X0h + (size_t)row * HID + lane * 8);
        union { f16x8 v; uint4 u; } O;
        #pragma unroll
        for (int q = 0; q < 8; ++q)
            O.v[q] = (_Float16)((1.0f - ALPHA) * (m[q] * scale) + ALPHA * (float)I.v[q]);
        *(uint4*)(Xi + (size_t)row * HID + lane * 8) = O.u;
    }
}

// ---------------- X = relu(Xi @ W') via MFMA 16x16x32 f16 ----------------
__global__ __launch_bounds__(256) void layer_gemm(
    const _Float16* __restrict__ Xi, const _Float16* __restrict__ Wp,
    _Float16* __restrict__ Xh)
{
    int lane = threadIdx.x & 63;
    int wv   = threadIdx.x >> 6;
    int r16  = lane & 15;
    int kgrp = lane >> 4;                    // 0..3
    f16x8 bf[4][2];
    #pragma unroll
    for (int n0 = 0; n0 < 4; ++n0)
        #pragma unroll
        for (int kh = 0; kh < 2; ++kh) {
            #pragma unroll
            for (int j = 0; j < 8; ++j)
                bf[n0][kh][j] = Wp[(kh * 32 + kgrp * 8 + j) * HID + n0 * 16 + r16];
        }
    int nwaves = gridDim.x * 4;
    for (int t = blockIdx.x * 4 + wv; t < N_NODES / 16; t += nwaves) {
        int row0 = t * 16;
        const _Float16* ap = Xi + (size_t)(row0 + r16) * HID + kgrp * 8;
        f16x8 a0 = *(const f16x8*)(ap);          // k = kgrp*8 .. +8
        f16x8 a1 = *(const f16x8*)(ap + 32);     // k += 32
        #pragma unroll
        for (int n0 = 0; n0 < 4; ++n0) {
            f32x4 acc = {0.f, 0.f, 0.f, 0.f};
            acc = __builtin_amdgcn_mfma_f32_16x16x32_f16(a0, bf[n0][0], acc, 0, 0, 0);
            acc = __builtin_amdgcn_mfma_f32_16x16x32_f16(a1, bf[n0][1], acc, 0, 0, 0);
            #pragma unroll
            for (int r = 0; r < 4; ++r) {
                float y = acc[r] > 0.f ? acc[r] : 0.f;
                Xh[(size_t)(row0 + kgrp * 4 + r) * HID + n0 * 16 + r16] = (_Float16)y;
            }
        }
    }
}

// ---------------- out = Xh @ Wout + bout via MFMA (N=40 -> 3 n-tiles) ----------------
__global__ __launch_bounds__(256) void out_gemm(
    const _Float16* __restrict__ Xh, const float* __restrict__ Wout,
    const float* __restrict__ bout, float* __restrict__ out)
{
    int lane = threadIdx.x & 63;
    int wv   = threadIdx.x >> 6;
    int r16  = lane & 15;
    int kgrp = lane >> 4;
    f16x8 bf[3][2];
    float bias[3];
    #pragma unroll
    for (int n0 = 0; n0 < 3; ++n0) {
        int col = n0 * 16 + r16;
        bias[n0] = (col < NCLS) ? bout[col] : 0.f;
        #pragma unroll
        for (int kh = 0; kh < 2; ++kh)
            #pragma unroll
            for (int j = 0; j < 8; ++j) {
                int k = kh * 32 + kgrp * 8 + j;
                bf[n0][kh][j] = (col < NCLS) ? (_Float16)Wout[k * NCLS + col] : (_Float16)0.f;
            }
    }
    int nwaves = gridDim.x * 4;
    for (int t = blockIdx.x * 4 + wv; t < N_NODES / 16; t += nwaves) {
        int row0 = t * 16;
        const _Float16* ap = Xh + (size_t)(row0 + r16) * HID + kgrp * 8;
        f16x8 a0 = *(const f16x8*)(ap);
        f16x8 a1 = *(const f16x8*)(ap + 32);
        #pragma unroll
        for (int n0 = 0; n0 < 3; ++n0) {
            f32x4 acc = {0.f, 0.f, 0.f, 0.f};
            acc = __builtin_amdgcn_mfma_f32_16x16x32_f16(a0, bf[n0][0], acc, 0, 0, 0);
            acc = __builtin_amdgcn_mfma_f32_16x16x32_f16(a1, bf[n0][1], acc, 0, 0, 0);
            int col = n0 * 16 + r16;
            if (col < NCLS) {
                #pragma unroll
                for (int r = 0; r < 4; ++r)
                    out[(size_t)(row0 + kgrp * 4 + r) * NCLS + col] = acc[r] + bias[n0];
            }
        }
    }
}

extern "C" void kernel_launch(void* const* d_in, const int* in_sizes, int n_in,
                              void* d_out, int out_size, void* d_ws, size_t ws_size,
                              hipStream_t stream)
{
    const float* x      = (const float*)d_in[0];
    const int*   vertex = (const int*)  d_in[1];
    const int*   edges  = (const int*)  d_in[2];
    const float* W0     = (const float*)d_in[3];
    const float* b0     = (const float*)d_in[4];
    const float* Ws     = (const float*)d_in[5];
    const float* Wout   = (const float*)d_in[6];
    const float* bout   = (const float*)d_in[7];
    float* out = (float*)d_out;

    char* ws = (char*)d_ws;
    unsigned long long* binned = (unsigned long long*)ws; ws += (size_t)NNZ_C * 8;
    _Float16*  X0h  = (_Float16*)ws;  ws += (size_t)N_NODES * HID * 2;
    _Float16*  Xh   = (_Float16*)ws;  ws += (size_t)N_NODES * HID * 2;
    _Float16*  Xi   = (_Float16*)ws;  ws += (size_t)N_NODES * HID * 2;
    __half*    Xeh  = (__half*)ws;    ws += (size_t)N_EDGES * HID * 2;
    _Float16*  Wp   = (_Float16*)ws;  ws += (size_t)NLAYER * HID * HID * 2;
    int*   adj_e  = (int*)ws;     ws += (size_t)NNZ_C * 4;
    int*   adj_v  = (int*)ws;     ws += (size_t)NNZ_C * 4;
    int*   off_e  = (int*)ws;     ws += (size_t)(N_EDGES + 1) * 4;
    int*   off_v  = (int*)ws;     ws += (size_t)(N_NODES + 1) * 4;
    float* inv_e  = (float*)ws;   ws += (size_t)N_EDGES * 4;
    float* inv_v  = (float*)ws;   ws += (size_t)N_NODES * 4;
    int*   gcnt   = (int*)ws;     ws += (size_t)NB_TOT * 4;
    int*   boff_e = (int*)ws;     ws += (size_t)(NB_E + 1) * 4;
    int*   boff_v = (int*)ws;     ws += (size_t)(NB_V + 1) * 4;
    int*   curb   = (int*)ws;     ws += (size_t)NB_TOT * 4;

    const int p1_grid = (NNZ_C + 4095) / 4096;   // 245

    // ---- CSR build ----
    hipMemsetAsync(gcnt, 0, (size_t)NB_TOT * 4, stream);
    bucket_hist<<<p1_grid, 256, 0, stream>>>(vertex, edges, gcnt);
    bucket_scan<<<1, 1024, 0, stream>>>(gcnt, boff_e, boff_v, curb);

    bin_pass1<<<p1_grid, 256, 0, stream>>>(edges, vertex, ESHIFT, NB_E, curb, binned);
    bin_pass2f<<<NB_E, 256, 0, stream>>>(binned, boff_e, ESHIFT, N_EDGES, off_e, inv_e, adj_e);
    bin_pass1<<<p1_grid, 256, 0, stream>>>(vertex, edges, VSHIFT, NB_V, curb + NB_E, binned);
    bin_pass2f<<<NB_V, 256, 0, stream>>>(binned, boff_v, VSHIFT, N_NODES, off_v, inv_v, adj_v);

    float be0 = logf(0.5f / 1.f + 1.0f);
    float be1 = logf(0.5f / 2.f + 1.0f);
    float be2 = logf(0.5f / 3.f + 1.0f);
    float be3 = logf(0.5f / 4.f + 1.0f);
    make_wp<<<NLAYER, 256, 0, stream>>>(Ws, Wp, be0, be1, be2, be3);

    input_gemm<<<391, 256, 0, stream>>>(x, W0, b0, X0h, Xh);

    for (int l = 0; l < NLAYER; ++l) {
        edge_gather<<<N_EDGES / 4, 256, 0, stream>>>((__half*)Xh, adj_e, off_e, inv_e, Xeh);
        node_gather<<<N_NODES / 4, 256, 0, stream>>>(
            Xeh, adj_v, off_v, inv_v, X0h, Xi);
        layer_gemm<<<391, 256, 0, stream>>>(Xi, Wp + (size_t)l * HID * HID, Xh);
    }

    out_gemm<<<391, 256, 0, stream>>>(Xh, Wout, bout, out);
}